// Round 1
// baseline (620.272 us; speedup 1.0000x reference)
//
#include <hip/hip_runtime.h>

// ---------------------------------------------------------------------------
// HetGAT critic on MI355X (gfx950), bf16-MFMA implementation.
//
// Algebraic simplification: softmax(axis=1) + einsum('bij,bjf->bf') makes the
// attention sum to exactly 1 per column => h_prime = (sum_nodes emb) @ gat_w.
// gat_a / adj / leaky_relu / softmax are dead code.
//
// GRU: gi precomputed as parallel GEMM; time scan runs per-block (16 batch
// rows/block, no cross-block sync), whh fragments loop-invariant in regs,
// h state kept in f32 registers, h broadcast through LDS for the next step's
// A-fragments. Layer-1 scan accumulates sum_t h_t directly (emb never stored).
// BS branch: T=1, h0=0 for both layers => gh == bhh (whh unused).
//
// MFMA v_mfma_f32_16x16x32_bf16 layouts:
//   A[m][k]: m=lane&15, k=(lane>>4)*8+i   (8 contiguous bf16 per lane)
//   B[k][n]: n=lane&15, k=(lane>>4)*8+i   (weights stored transposed [N][K])
//   D[m][n]: n=lane&15, m=(lane>>4)*4+reg
//
// Workspace (~142 MB required):
//   [0, 1MB)              bf16 weights (converted/transposed by k_prep)
//   [1MB, 34.6MB)         X2  : [131072,128] bf16 (l2 out; later Y0 in-place)
//   [34.6MB, 135.3MB)     GI  : [131072,384] bf16
//   [135.3MB, 136.3MB)    X2BS: [4096,128] bf16
//   [136.3MB, 137.4MB)    H0BS: [4096,128] bf16
//   [137.4MB, 139.5MB)    HBS : [4096,128] f32
//   [139.5MB, 141.6MB)    SSUM: [4096,128] f32 (sum_t of UE layer-1 h)
// ---------------------------------------------------------------------------

typedef unsigned short u16;
typedef __bf16  bf16x8  __attribute__((ext_vector_type(8)));
typedef short   short8  __attribute__((ext_vector_type(8)));
typedef float   floatx4 __attribute__((ext_vector_type(4)));

#define DEVI __device__ __forceinline__
#define MFMA(a, b, c) __builtin_amdgcn_mfma_f32_16x16x32_bf16((a), (b), (c), 0, 0, 0)

DEVI u16 f2b(float f) {                       // f32 -> bf16 bits, RNE
    unsigned u = __float_as_uint(f);
    u += 0x7fffu + ((u >> 16) & 1u);
    return (u16)(u >> 16);
}
DEVI float b2f(u16 s) { return __uint_as_float(((unsigned)s) << 16); }
DEVI float sigm(float x) { return 1.f / (1.f + __expf(-x)); }
DEVI float tanh_(float x) { return 1.f - 2.f / (__expf(2.f * x) + 1.f); }

DEVI bf16x8 ldfrag(const u16* q) {            // 8 contiguous bf16 (16B aligned)
    return *reinterpret_cast<const bf16x8*>(q);
}
DEVI bf16x8 ldfrag_f32(const float* q) {      // 8 contiguous f32 -> bf16 frag
    float4 u = *reinterpret_cast<const float4*>(q);
    float4 v = *reinterpret_cast<const float4*>(q + 4);
    short8 pk;
    pk[0] = (short)f2b(u.x); pk[1] = (short)f2b(u.y);
    pk[2] = (short)f2b(u.z); pk[3] = (short)f2b(u.w);
    pk[4] = (short)f2b(v.x); pk[5] = (short)f2b(v.y);
    pk[6] = (short)f2b(v.z); pk[7] = (short)f2b(v.w);
    return __builtin_bit_cast(bf16x8, pk);
}

// bf16 weight offsets inside ws (elements)
enum : int {
    O_UE_W1T  = 0,        // [128][160]
    O_UE_W2T  = 20480,    // [128][128]
    O_UE_WIH0 = 36864,    // [384][128]
    O_UE_WHH0 = 86016,
    O_UE_WIH1 = 135168,
    O_UE_WHH1 = 184320,
    O_BS_W1T  = 233472,   // [128][320]
    O_BS_W2T  = 274432,
    O_BS_WIH0 = 290816,
    O_BS_WIH1 = 339968,
    O_GATWT   = 389120,   // [128][128]
    O_EV1T    = 405504,   // [128][128]
};
// ws byte offsets
#define WB_X2   1048576u
#define WB_GI   34603008u
#define WB_X2BS 135266304u
#define WB_H0BS 136314880u
#define WB_HBS  137363456u
#define WB_SSUM 139460608u

// ---------------------------------------------------------------------------
__global__ __launch_bounds__(256) void k_prep(
    const float* __restrict__ ue1, const float* __restrict__ ue2,
    const float* __restrict__ uw0, const float* __restrict__ uh0,
    const float* __restrict__ uw1, const float* __restrict__ uh1,
    const float* __restrict__ bs1, const float* __restrict__ bs2,
    const float* __restrict__ bw0, const float* __restrict__ bw1,
    const float* __restrict__ gw,  const float* __restrict__ e1,
    u16* __restrict__ out)
{
    const int tid = blockIdx.x * blockDim.x + threadIdx.x;
    const int stride = gridDim.x * blockDim.x;
    auto cvt = [&](const float* s, int off, int n) {
        for (int i = tid; i < n; i += stride) out[off + i] = f2b(s[i]);
    };
    auto tcv = [&](const float* s, int off, int K, int N) {  // [K,N] -> [N,K]
        const int tot = K * N;
        for (int i = tid; i < tot; i += stride) {
            int nn = i / K, kk = i - nn * K;
            out[off + i] = f2b(s[kk * N + nn]);
        }
    };
    tcv(ue1, O_UE_W1T, 160, 128);  tcv(ue2, O_UE_W2T, 128, 128);
    cvt(uw0, O_UE_WIH0, 49152);    cvt(uh0, O_UE_WHH0, 49152);
    cvt(uw1, O_UE_WIH1, 49152);    cvt(uh1, O_UE_WHH1, 49152);
    tcv(bs1, O_BS_W1T, 320, 128);  tcv(bs2, O_BS_W2T, 128, 128);
    cvt(bw0, O_BS_WIH0, 49152);    cvt(bw1, O_BS_WIH1, 49152);
    tcv(gw,  O_GATWT, 128, 128);   tcv(e1,  O_EV1T, 128, 128);
}

// ---------------------------------------------------------------------------
// UE l1(relu) + l2(sigmoid), fused.  M=131072 rows (b*32+t), K=160 then 128.
__global__ __launch_bounds__(256, 2) void k_ue_l1l2(
    const float* __restrict__ s, const float* __restrict__ a,
    const u16* __restrict__ W1T, const float* __restrict__ b1,
    const u16* __restrict__ W2T, const float* __restrict__ b2,
    u16* __restrict__ X2)
{
    __shared__ __align__(16) u16 hb[4][16][136];
    const int w = threadIdx.x >> 6, lane = threadIdx.x & 63;
    const int lm = lane & 15, lg = lane >> 4;
    const int r0 = blockIdx.x * 64 + w * 16;
    const int r = r0 + lm, bb = r >> 5, tt = r & 31;
    const float* srow = s + bb * 4352 + tt * 128 + lg * 8;
    const float* arow = a + bb * 1088 + tt * 32 + lg * 8;

    bf16x8 af[5];
#pragma unroll
    for (int ks = 0; ks < 4; ++ks) af[ks] = ldfrag_f32(srow + ks * 32);
    af[4] = ldfrag_f32(arow);

    const u16* wb1 = W1T + lm * 160 + lg * 8;
#pragma unroll
    for (int n = 0; n < 8; ++n) {
        floatx4 acc = {0.f, 0.f, 0.f, 0.f};
#pragma unroll
        for (int ks = 0; ks < 5; ++ks)
            acc = MFMA(af[ks], ldfrag(wb1 + n * 2560 + ks * 32), acc);
        const float bias = b1[n * 16 + lm];
#pragma unroll
        for (int i = 0; i < 4; ++i) {
            float x = acc[i] + bias;
            hb[w][lg * 4 + i][n * 16 + lm] = f2b(x > 0.f ? x : 0.f);
        }
    }
    __syncthreads();

    bf16x8 af2[4];
#pragma unroll
    for (int ks = 0; ks < 4; ++ks) af2[ks] = ldfrag(&hb[w][lm][ks * 32 + lg * 8]);
    const u16* wb2 = W2T + lm * 128 + lg * 8;
#pragma unroll
    for (int n = 0; n < 8; ++n) {
        floatx4 acc = {0.f, 0.f, 0.f, 0.f};
#pragma unroll
        for (int ks = 0; ks < 4; ++ks)
            acc = MFMA(af2[ks], ldfrag(wb2 + n * 2048 + ks * 32), acc);
        const float bias = b2[n * 16 + lm];
#pragma unroll
        for (int i = 0; i < 4; ++i) {
            float v = sigm(acc[i] + bias);
            X2[(unsigned)(r0 + lg * 4 + i) * 128u + n * 16 + lm] = f2b(v);
        }
    }
}

// ---------------------------------------------------------------------------
// GI = X @ WIH^T + bih.  M=131072, N=384, K=128.  Block=64 rows, 4 waves:
// wave = (m-half, n-half): 2 M-tiles x 12 N-tiles each.
__global__ __launch_bounds__(256, 2) void k_gi(
    const u16* __restrict__ X, const u16* __restrict__ WIH,
    const float* __restrict__ bih, u16* __restrict__ GI)
{
    const int w = threadIdx.x >> 6, lane = threadIdx.x & 63;
    const int lm = lane & 15, lg = lane >> 4;
    const int mh = w >> 1, nh = w & 1;
    const int r0 = blockIdx.x * 64 + mh * 32;

    bf16x8 a0[4], a1[4];
    const u16* xr = X + (unsigned)(r0 + lm) * 128u + lg * 8;
#pragma unroll
    for (int ks = 0; ks < 4; ++ks) {
        a0[ks] = ldfrag(xr + ks * 32);
        a1[ks] = ldfrag(xr + 16 * 128 + ks * 32);
    }
    floatx4 acc[12][2];
#pragma unroll
    for (int j = 0; j < 12; ++j) {
        acc[j][0] = floatx4{0.f, 0.f, 0.f, 0.f};
        acc[j][1] = floatx4{0.f, 0.f, 0.f, 0.f};
    }
    const u16* wbp = WIH + (nh * 192 + lm) * 128 + lg * 8;
#pragma unroll
    for (int j = 0; j < 12; ++j) {
#pragma unroll
        for (int ks = 0; ks < 4; ++ks) {
            bf16x8 bf = ldfrag(wbp + j * 2048 + ks * 32);
            acc[j][0] = MFMA(a0[ks], bf, acc[j][0]);
            acc[j][1] = MFMA(a1[ks], bf, acc[j][1]);
        }
    }
#pragma unroll
    for (int j = 0; j < 12; ++j) {
        const int col = (nh * 12 + j) * 16 + lm;
        const float bias = bih[col];
#pragma unroll
        for (int mt = 0; mt < 2; ++mt)
#pragma unroll
            for (int i = 0; i < 4; ++i) {
                unsigned row = (unsigned)(r0 + mt * 16 + lg * 4 + i);
                GI[row * 384u + col] = f2b(acc[j][mt][i] + bias);
            }
    }
}

// ---------------------------------------------------------------------------
// GRU time scan.  Block = 16 batch rows, 4 waves; wave w owns dh cols
// [w*32, w*32+32) across all 3 gates.  whh fragments loop-invariant in regs.
// MODE 0: write Y[b*32+t,:].  MODE 1: accumulate sum_t h -> Ssum (f32).
template <int MODE>
__global__ __launch_bounds__(256, 2) void k_scan(
    const u16* __restrict__ GI, const u16* __restrict__ WHH,
    const float* __restrict__ bhh, u16* __restrict__ Y, float* __restrict__ Ssum)
{
    __shared__ __align__(16) u16 hb[16][136];
    const int w = threadIdx.x >> 6, lane = threadIdx.x & 63;
    const int lm = lane & 15, lg = lane >> 4;
    const int b0 = blockIdx.x * 16;

    bf16x8 bw[6][4];   // 6 n-tiles (r,r,z,z,n,n) x 4 k-frags
#pragma unroll
    for (int jj = 0; jj < 6; ++jj) {
        const int nc = (jj >> 1) * 128 + w * 32 + (jj & 1) * 16;
#pragma unroll
        for (int ks = 0; ks < 4; ++ks)
            bw[jj][ks] = ldfrag(WHH + (nc + lm) * 128 + ks * 32 + lg * 8);
    }
    for (int i = threadIdx.x; i < 16 * 136; i += 256) ((u16*)hb)[i] = 0;

    float bh_r[2], bh_z[2], bh_n[2];
#pragma unroll
    for (int ct = 0; ct < 2; ++ct) {
        const int c = w * 32 + ct * 16 + lm;
        bh_r[ct] = bhh[c]; bh_z[ct] = bhh[128 + c]; bh_n[ct] = bhh[256 + c];
    }
    float hreg[2][4] = {}, ssum[2][4] = {};
    unsigned gibase[4], ybase[4];
#pragma unroll
    for (int i = 0; i < 4; ++i) {
        gibase[i] = (unsigned)(b0 + lg * 4 + i) * 32u * 384u;
        ybase[i]  = (unsigned)(b0 + lg * 4 + i) * 32u * 128u;
    }
    __syncthreads();

    for (int t = 0; t < 32; ++t) {
        bf16x8 af[4];
#pragma unroll
        for (int ks = 0; ks < 4; ++ks) af[ks] = ldfrag(&hb[lm][ks * 32 + lg * 8]);
        floatx4 acc[6];
#pragma unroll
        for (int jj = 0; jj < 6; ++jj) acc[jj] = floatx4{0.f, 0.f, 0.f, 0.f};
#pragma unroll
        for (int jj = 0; jj < 6; ++jj)
#pragma unroll
            for (int ks = 0; ks < 4; ++ks)
                acc[jj] = MFMA(af[ks], bw[jj][ks], acc[jj]);

        float gv[2][3][4];
#pragma unroll
        for (int ct = 0; ct < 2; ++ct) {
            const int c = w * 32 + ct * 16 + lm;
#pragma unroll
            for (int i = 0; i < 4; ++i) {
                const unsigned base = gibase[i] + (unsigned)t * 384u;
                gv[ct][0][i] = b2f(GI[base + c]);
                gv[ct][1][i] = b2f(GI[base + 128 + c]);
                gv[ct][2][i] = b2f(GI[base + 256 + c]);
            }
        }
        __syncthreads();   // everyone done reading hb (A-frags consumed by MFMA)

#pragma unroll
        for (int ct = 0; ct < 2; ++ct) {
            const int c = w * 32 + ct * 16 + lm;
#pragma unroll
            for (int i = 0; i < 4; ++i) {
                const float rr = sigm(gv[ct][0][i] + acc[ct][i]     + bh_r[ct]);
                const float zz = sigm(gv[ct][1][i] + acc[2 + ct][i] + bh_z[ct]);
                const float nn = tanh_(gv[ct][2][i] + rr * (acc[4 + ct][i] + bh_n[ct]));
                const float hn = (1.f - zz) * nn + zz * hreg[ct][i];
                hreg[ct][i] = hn;
                if (MODE == 1) ssum[ct][i] += hn;
                const u16 hv = f2b(hn);
                hb[lg * 4 + i][c] = hv;
                if (MODE == 0) Y[ybase[i] + (unsigned)t * 128u + c] = hv;
            }
        }
        __syncthreads();   // writes visible before next step's reads
    }
    if (MODE == 1) {
#pragma unroll
        for (int ct = 0; ct < 2; ++ct) {
            const int c = w * 32 + ct * 16 + lm;
#pragma unroll
            for (int i = 0; i < 4; ++i)
                Ssum[(unsigned)(b0 + lg * 4 + i) * 128u + c] = ssum[ct][i];
        }
    }
}

// ---------------------------------------------------------------------------
// BS l1(relu, K=320) + l2(sigmoid).  M=4096 rows.
__global__ __launch_bounds__(256, 2) void k_bs_l1l2(
    const float* __restrict__ s, const float* __restrict__ a,
    const u16* __restrict__ W1T, const float* __restrict__ b1,
    const u16* __restrict__ W2T, const float* __restrict__ b2,
    u16* __restrict__ X2)
{
    __shared__ __align__(16) u16 hb[4][16][136];
    const int w = threadIdx.x >> 6, lane = threadIdx.x & 63;
    const int lm = lane & 15, lg = lane >> 4;
    const int r0 = blockIdx.x * 64 + w * 16;
    const float* srow = s + (r0 + lm) * 4352 + 4096 + lg * 8;
    const float* arow = a + (r0 + lm) * 1088 + 1024 + lg * 8;

    bf16x8 af[10];
#pragma unroll
    for (int ks = 0; ks < 8; ++ks) af[ks] = ldfrag_f32(srow + ks * 32);
    af[8] = ldfrag_f32(arow);
    af[9] = ldfrag_f32(arow + 32);

    const u16* wb1 = W1T + lm * 320 + lg * 8;
#pragma unroll
    for (int n = 0; n < 8; ++n) {
        floatx4 acc = {0.f, 0.f, 0.f, 0.f};
#pragma unroll
        for (int ks = 0; ks < 10; ++ks)
            acc = MFMA(af[ks], ldfrag(wb1 + n * 5120 + ks * 32), acc);
        const float bias = b1[n * 16 + lm];
#pragma unroll
        for (int i = 0; i < 4; ++i) {
            float x = acc[i] + bias;
            hb[w][lg * 4 + i][n * 16 + lm] = f2b(x > 0.f ? x : 0.f);
        }
    }
    __syncthreads();

    bf16x8 af2[4];
#pragma unroll
    for (int ks = 0; ks < 4; ++ks) af2[ks] = ldfrag(&hb[w][lm][ks * 32 + lg * 8]);
    const u16* wb2 = W2T + lm * 128 + lg * 8;
#pragma unroll
    for (int n = 0; n < 8; ++n) {
        floatx4 acc = {0.f, 0.f, 0.f, 0.f};
#pragma unroll
        for (int ks = 0; ks < 4; ++ks)
            acc = MFMA(af2[ks], ldfrag(wb2 + n * 2048 + ks * 32), acc);
        const float bias = b2[n * 16 + lm];
#pragma unroll
        for (int i = 0; i < 4; ++i) {
            float v = sigm(acc[i] + bias);
            X2[(unsigned)(r0 + lg * 4 + i) * 128u + n * 16 + lm] = f2b(v);
        }
    }
}

// ---------------------------------------------------------------------------
// BS GRU single step with h_prev = 0 (true for both layers at T=1):
// h = (1-z)*tanh(gi_n + bih_n + r*bhh_n), r/z = sigm(gi + bih + bhh).
template <int OUTF32>
__global__ __launch_bounds__(256, 2) void k_bs_gru(
    const u16* __restrict__ X, const u16* __restrict__ WIH,
    const float* __restrict__ bih, const float* __restrict__ bhh,
    u16* __restrict__ Hb, float* __restrict__ Hf)
{
    const int w = threadIdx.x >> 6, lane = threadIdx.x & 63;
    const int lm = lane & 15, lg = lane >> 4;
    const int r0 = blockIdx.x * 64 + w * 16;

    bf16x8 ax[4];
    const u16* xr = X + (unsigned)(r0 + lm) * 128u + lg * 8;
#pragma unroll
    for (int ks = 0; ks < 4; ++ks) ax[ks] = ldfrag(xr + ks * 32);

    floatx4 acc[24];  // j<8: r-gate cols, 8..15: z, 16..23: n
#pragma unroll
    for (int j = 0; j < 24; ++j) acc[j] = floatx4{0.f, 0.f, 0.f, 0.f};
    const u16* wbp = WIH + lm * 128 + lg * 8;
#pragma unroll
    for (int j = 0; j < 24; ++j)
#pragma unroll
        for (int ks = 0; ks < 4; ++ks)
            acc[j] = MFMA(ax[ks], ldfrag(wbp + j * 2048 + ks * 32), acc[j]);

#pragma unroll
    for (int ct = 0; ct < 8; ++ct) {
        const int c = ct * 16 + lm;
        const float br = bih[c] + bhh[c];
        const float bz = bih[128 + c] + bhh[128 + c];
        const float bni = bih[256 + c], bnh = bhh[256 + c];
#pragma unroll
        for (int i = 0; i < 4; ++i) {
            const float rr = sigm(acc[ct][i] + br);
            const float zz = sigm(acc[8 + ct][i] + bz);
            const float nn = tanh_(acc[16 + ct][i] + bni + rr * bnh);
            const float h = (1.f - zz) * nn;
            const unsigned row = (unsigned)(r0 + lg * 4 + i);
            if (OUTF32) Hf[row * 128u + c] = h;
            else        Hb[row * 128u + c] = f2b(h);
        }
    }
}

// ---------------------------------------------------------------------------
// Final: S = SSUM + HBS;  out = relu(elu(S@gat_w) @ ev1 + b1) @ ev2 + b2.
__global__ __launch_bounds__(256, 2) void k_final(
    const float* __restrict__ Ssum, const float* __restrict__ HBS,
    const u16* __restrict__ GATWT, const u16* __restrict__ EV1T,
    const float* __restrict__ ev1b, const float* __restrict__ ev2w,
    const float* __restrict__ ev2b, float* __restrict__ out)
{
    __shared__ __align__(16) u16 hb[4][16][136];
    __shared__ float xb[4][16][132];
    const int w = threadIdx.x >> 6, lane = threadIdx.x & 63;
    const int lm = lane & 15, lg = lane >> 4;
    const int r0 = blockIdx.x * 64 + w * 16;

    const float* p1 = Ssum + (unsigned)(r0 + lm) * 128u + lg * 8;
    const float* p2 = HBS  + (unsigned)(r0 + lm) * 128u + lg * 8;
    bf16x8 af[4];
#pragma unroll
    for (int ks = 0; ks < 4; ++ks) {
        float4 u = *reinterpret_cast<const float4*>(p1 + ks * 32);
        float4 u2 = *reinterpret_cast<const float4*>(p1 + ks * 32 + 4);
        float4 v = *reinterpret_cast<const float4*>(p2 + ks * 32);
        float4 v2 = *reinterpret_cast<const float4*>(p2 + ks * 32 + 4);
        short8 pk;
        pk[0] = (short)f2b(u.x + v.x); pk[1] = (short)f2b(u.y + v.y);
        pk[2] = (short)f2b(u.z + v.z); pk[3] = (short)f2b(u.w + v.w);
        pk[4] = (short)f2b(u2.x + v2.x); pk[5] = (short)f2b(u2.y + v2.y);
        pk[6] = (short)f2b(u2.z + v2.z); pk[7] = (short)f2b(u2.w + v2.w);
        af[ks] = __builtin_bit_cast(bf16x8, pk);
    }
    const u16* gwp = GATWT + lm * 128 + lg * 8;
#pragma unroll
    for (int n = 0; n < 8; ++n) {
        floatx4 acc = {0.f, 0.f, 0.f, 0.f};
#pragma unroll
        for (int ks = 0; ks < 4; ++ks)
            acc = MFMA(af[ks], ldfrag(gwp + n * 2048 + ks * 32), acc);
#pragma unroll
        for (int i = 0; i < 4; ++i) {
            float x = acc[i];
            x = x > 0.f ? x : (__expf(x) - 1.f);            // elu
            hb[w][lg * 4 + i][n * 16 + lm] = f2b(x);
        }
    }
    __syncthreads();

    bf16x8 af2[4];
#pragma unroll
    for (int ks = 0; ks < 4; ++ks) af2[ks] = ldfrag(&hb[w][lm][ks * 32 + lg * 8]);
    const u16* e1p = EV1T + lm * 128 + lg * 8;
#pragma unroll
    for (int n = 0; n < 8; ++n) {
        floatx4 acc = {0.f, 0.f, 0.f, 0.f};
#pragma unroll
        for (int ks = 0; ks < 4; ++ks)
            acc = MFMA(af2[ks], ldfrag(e1p + n * 2048 + ks * 32), acc);
        const float bias = ev1b[n * 16 + lm];
#pragma unroll
        for (int i = 0; i < 4; ++i) {
            float v = acc[i] + bias;
            xb[w][lg * 4 + i][n * 16 + lm] = v > 0.f ? v : 0.f;  // relu
        }
    }
    __syncthreads();

    float sacc = 0.f;
#pragma unroll
    for (int k = 0; k < 32; ++k) {
        const int c = lg * 32 + k;
        sacc += xb[w][lm][c] * ev2w[c];
    }
    sacc += __shfl_xor(sacc, 16, 64);
    sacc += __shfl_xor(sacc, 32, 64);
    if (lg == 0) out[r0 + lm] = sacc + ev2b[0];
}

// ---------------------------------------------------------------------------
extern "C" void kernel_launch(void* const* d_in, const int* in_sizes, int n_in,
                              void* d_out, int out_size, void* d_ws, size_t ws_size,
                              hipStream_t stream)
{
    (void)in_sizes; (void)n_in; (void)out_size; (void)ws_size;
    const float* s       = (const float*)d_in[0];
    const float* a       = (const float*)d_in[1];
    const float* ue_l1_w = (const float*)d_in[2];
    const float* ue_l1_b = (const float*)d_in[3];
    const float* ue_l2_w = (const float*)d_in[4];
    const float* ue_l2_b = (const float*)d_in[5];
    const float* ue_wih0 = (const float*)d_in[6];
    const float* ue_whh0 = (const float*)d_in[7];
    const float* ue_bih0 = (const float*)d_in[8];
    const float* ue_bhh0 = (const float*)d_in[9];
    const float* ue_wih1 = (const float*)d_in[10];
    const float* ue_whh1 = (const float*)d_in[11];
    const float* ue_bih1 = (const float*)d_in[12];
    const float* ue_bhh1 = (const float*)d_in[13];
    const float* bs_l1_w = (const float*)d_in[14];
    const float* bs_l1_b = (const float*)d_in[15];
    const float* bs_l2_w = (const float*)d_in[16];
    const float* bs_l2_b = (const float*)d_in[17];
    const float* bs_wih0 = (const float*)d_in[18];
    const float* bs_bih0 = (const float*)d_in[20];
    const float* bs_bhh0 = (const float*)d_in[21];
    const float* bs_wih1 = (const float*)d_in[22];
    const float* bs_bih1 = (const float*)d_in[24];
    const float* bs_bhh1 = (const float*)d_in[25];
    const float* gat_w   = (const float*)d_in[26];
    const float* ev1_w   = (const float*)d_in[29];
    const float* ev1_b   = (const float*)d_in[30];
    const float* ev2_w   = (const float*)d_in[31];
    const float* ev2_b   = (const float*)d_in[32];

    char* ws = (char*)d_ws;
    u16*   wb   = (u16*)ws;
    u16*   X2   = (u16*)(ws + WB_X2);
    u16*   GI   = (u16*)(ws + WB_GI);
    u16*   X2BS = (u16*)(ws + WB_X2BS);
    u16*   H0BS = (u16*)(ws + WB_H0BS);
    float* HBS  = (float*)(ws + WB_HBS);
    float* SSUM = (float*)(ws + WB_SSUM);

    k_prep<<<256, 256, 0, stream>>>(ue_l1_w, ue_l2_w, ue_wih0, ue_whh0,
                                    ue_wih1, ue_whh1, bs_l1_w, bs_l2_w,
                                    bs_wih0, bs_wih1, gat_w, ev1_w, wb);
    k_ue_l1l2<<<2048, 256, 0, stream>>>(s, a, wb + O_UE_W1T, ue_l1_b,
                                        wb + O_UE_W2T, ue_l2_b, X2);
    k_gi<<<2048, 256, 0, stream>>>(X2, wb + O_UE_WIH0, ue_bih0, GI);
    k_scan<0><<<256, 256, 0, stream>>>(GI, wb + O_UE_WHH0, ue_bhh0, X2, nullptr);
    k_gi<<<2048, 256, 0, stream>>>(X2, wb + O_UE_WIH1, ue_bih1, GI);
    k_scan<1><<<256, 256, 0, stream>>>(GI, wb + O_UE_WHH1, ue_bhh1, nullptr, SSUM);
    k_bs_l1l2<<<64, 256, 0, stream>>>(s, a, wb + O_BS_W1T, bs_l1_b,
                                      wb + O_BS_W2T, bs_l2_b, X2BS);
    k_bs_gru<0><<<64, 256, 0, stream>>>(X2BS, wb + O_BS_WIH0, bs_bih0, bs_bhh0,
                                        H0BS, nullptr);
    k_bs_gru<1><<<64, 256, 0, stream>>>(H0BS, wb + O_BS_WIH1, bs_bih1, bs_bhh1,
                                        nullptr, HBS);
    k_final<<<64, 256, 0, stream>>>(SSUM, HBS, wb + O_GATWT, wb + O_EV1T,
                                    ev1_b, ev2_w, ev2_b, (float*)d_out);
}

// Round 2
// 541.680 us; speedup vs baseline: 1.1451x; 1.1451x over previous
//
#include <hip/hip_runtime.h>

// ---------------------------------------------------------------------------
// HetGAT critic on MI355X (gfx950), bf16-MFMA implementation.
//
// Algebraic simplification: softmax(axis=1) + einsum('bij,bjf->bf') makes the
// attention sum to exactly 1 per column => h_prime = (sum_nodes emb) @ gat_w.
// gat_a / adj / leaky_relu / softmax are dead code.
//
// GRU: gi precomputed as parallel GEMM; time scan runs per-block (16 batch
// rows/block, no cross-block sync), whh fragments loop-invariant in regs,
// h state kept in f32 registers, h broadcast through LDS for the next step's
// A-fragments. Layer-1 scan accumulates sum_t h_t directly (emb never stored).
// BS branch: T=1, h0=0 for both layers => gh == bhh (whh unused).
//
// Round-1 scan rewrite: 8 waves/block (wave owns 16 cols x 3 gates),
// GI prefetched one step ahead via pointer-increment scalar loads,
// double-buffered h in LDS with a single lgkm-only barrier per step
// (vmem prefetch/stores ride across the barrier).
//
// MFMA v_mfma_f32_16x16x32_bf16 layouts:
//   A[m][k]: m=lane&15, k=(lane>>4)*8+i   (8 contiguous bf16 per lane)
//   B[k][n]: n=lane&15, k=(lane>>4)*8+i   (weights stored transposed [N][K])
//   D[m][n]: n=lane&15, m=(lane>>4)*4+reg
// ---------------------------------------------------------------------------

typedef unsigned short u16;
typedef __bf16  bf16x8  __attribute__((ext_vector_type(8)));
typedef short   short8  __attribute__((ext_vector_type(8)));
typedef float   floatx4 __attribute__((ext_vector_type(4)));

#define DEVI __device__ __forceinline__
#define MFMA(a, b, c) __builtin_amdgcn_mfma_f32_16x16x32_bf16((a), (b), (c), 0, 0, 0)

DEVI u16 f2b(float f) {                       // f32 -> bf16 bits, RNE
    unsigned u = __float_as_uint(f);
    u += 0x7fffu + ((u >> 16) & 1u);
    return (u16)(u >> 16);
}
DEVI float b2f(u16 s) { return __uint_as_float(((unsigned)s) << 16); }
DEVI float sigm(float x) { return 1.f / (1.f + __expf(-x)); }
DEVI float tanh_(float x) { return 1.f - 2.f / (__expf(2.f * x) + 1.f); }

DEVI bf16x8 ldfrag(const u16* q) {            // 8 contiguous bf16 (16B aligned)
    return *reinterpret_cast<const bf16x8*>(q);
}
DEVI bf16x8 ldfrag_f32(const float* q) {      // 8 contiguous f32 -> bf16 frag
    float4 u = *reinterpret_cast<const float4*>(q);
    float4 v = *reinterpret_cast<const float4*>(q + 4);
    short8 pk;
    pk[0] = (short)f2b(u.x); pk[1] = (short)f2b(u.y);
    pk[2] = (short)f2b(u.z); pk[3] = (short)f2b(u.w);
    pk[4] = (short)f2b(v.x); pk[5] = (short)f2b(v.y);
    pk[6] = (short)f2b(v.z); pk[7] = (short)f2b(v.w);
    return __builtin_bit_cast(bf16x8, pk);
}

// bf16 weight offsets inside ws (elements)
enum : int {
    O_UE_W1T  = 0,        // [128][160]
    O_UE_W2T  = 20480,    // [128][128]
    O_UE_WIH0 = 36864,    // [384][128]
    O_UE_WHH0 = 86016,
    O_UE_WIH1 = 135168,
    O_UE_WHH1 = 184320,
    O_BS_W1T  = 233472,   // [128][320]
    O_BS_W2T  = 274432,
    O_BS_WIH0 = 290816,
    O_BS_WIH1 = 339968,
    O_GATWT   = 389120,   // [128][128]
    O_EV1T    = 405504,   // [128][128]
};
// ws byte offsets
#define WB_X2   1048576u
#define WB_GI   34603008u
#define WB_X2BS 135266304u
#define WB_H0BS 136314880u
#define WB_HBS  137363456u
#define WB_SSUM 139460608u

// ---------------------------------------------------------------------------
__global__ __launch_bounds__(256) void k_prep(
    const float* __restrict__ ue1, const float* __restrict__ ue2,
    const float* __restrict__ uw0, const float* __restrict__ uh0,
    const float* __restrict__ uw1, const float* __restrict__ uh1,
    const float* __restrict__ bs1, const float* __restrict__ bs2,
    const float* __restrict__ bw0, const float* __restrict__ bw1,
    const float* __restrict__ gw,  const float* __restrict__ e1,
    u16* __restrict__ out)
{
    const int tid = blockIdx.x * blockDim.x + threadIdx.x;
    const int stride = gridDim.x * blockDim.x;
    auto cvt = [&](const float* s, int off, int n) {
        for (int i = tid; i < n; i += stride) out[off + i] = f2b(s[i]);
    };
    auto tcv = [&](const float* s, int off, int K, int N) {  // [K,N] -> [N,K]
        const int tot = K * N;
        for (int i = tid; i < tot; i += stride) {
            int nn = i / K, kk = i - nn * K;
            out[off + i] = f2b(s[kk * N + nn]);
        }
    };
    tcv(ue1, O_UE_W1T, 160, 128);  tcv(ue2, O_UE_W2T, 128, 128);
    cvt(uw0, O_UE_WIH0, 49152);    cvt(uh0, O_UE_WHH0, 49152);
    cvt(uw1, O_UE_WIH1, 49152);    cvt(uh1, O_UE_WHH1, 49152);
    tcv(bs1, O_BS_W1T, 320, 128);  tcv(bs2, O_BS_W2T, 128, 128);
    cvt(bw0, O_BS_WIH0, 49152);    cvt(bw1, O_BS_WIH1, 49152);
    tcv(gw,  O_GATWT, 128, 128);   tcv(e1,  O_EV1T, 128, 128);
}

// ---------------------------------------------------------------------------
// UE l1(relu) + l2(sigmoid), fused.  M=131072 rows (b*32+t), K=160 then 128.
__global__ __launch_bounds__(256, 2) void k_ue_l1l2(
    const float* __restrict__ s, const float* __restrict__ a,
    const u16* __restrict__ W1T, const float* __restrict__ b1,
    const u16* __restrict__ W2T, const float* __restrict__ b2,
    u16* __restrict__ X2)
{
    __shared__ __align__(16) u16 hb[4][16][136];
    const int w = threadIdx.x >> 6, lane = threadIdx.x & 63;
    const int lm = lane & 15, lg = lane >> 4;
    const int r0 = blockIdx.x * 64 + w * 16;
    const int r = r0 + lm, bb = r >> 5, tt = r & 31;
    const float* srow = s + bb * 4352 + tt * 128 + lg * 8;
    const float* arow = a + bb * 1088 + tt * 32 + lg * 8;

    bf16x8 af[5];
#pragma unroll
    for (int ks = 0; ks < 4; ++ks) af[ks] = ldfrag_f32(srow + ks * 32);
    af[4] = ldfrag_f32(arow);

    const u16* wb1 = W1T + lm * 160 + lg * 8;
#pragma unroll
    for (int n = 0; n < 8; ++n) {
        floatx4 acc = {0.f, 0.f, 0.f, 0.f};
#pragma unroll
        for (int ks = 0; ks < 5; ++ks)
            acc = MFMA(af[ks], ldfrag(wb1 + n * 2560 + ks * 32), acc);
        const float bias = b1[n * 16 + lm];
#pragma unroll
        for (int i = 0; i < 4; ++i) {
            float x = acc[i] + bias;
            hb[w][lg * 4 + i][n * 16 + lm] = f2b(x > 0.f ? x : 0.f);
        }
    }
    __syncthreads();

    bf16x8 af2[4];
#pragma unroll
    for (int ks = 0; ks < 4; ++ks) af2[ks] = ldfrag(&hb[w][lm][ks * 32 + lg * 8]);
    const u16* wb2 = W2T + lm * 128 + lg * 8;
#pragma unroll
    for (int n = 0; n < 8; ++n) {
        floatx4 acc = {0.f, 0.f, 0.f, 0.f};
#pragma unroll
        for (int ks = 0; ks < 4; ++ks)
            acc = MFMA(af2[ks], ldfrag(wb2 + n * 2048 + ks * 32), acc);
        const float bias = b2[n * 16 + lm];
#pragma unroll
        for (int i = 0; i < 4; ++i) {
            float v = sigm(acc[i] + bias);
            X2[(unsigned)(r0 + lg * 4 + i) * 128u + n * 16 + lm] = f2b(v);
        }
    }
}

// ---------------------------------------------------------------------------
// GI = X @ WIH^T + bih.  M=131072, N=384, K=128.  Block=64 rows, 4 waves:
// wave = (m-half, n-half): 2 M-tiles x 12 N-tiles each.
__global__ __launch_bounds__(256, 2) void k_gi(
    const u16* __restrict__ X, const u16* __restrict__ WIH,
    const float* __restrict__ bih, u16* __restrict__ GI)
{
    const int w = threadIdx.x >> 6, lane = threadIdx.x & 63;
    const int lm = lane & 15, lg = lane >> 4;
    const int mh = w >> 1, nh = w & 1;
    const int r0 = blockIdx.x * 64 + mh * 32;

    bf16x8 a0[4], a1[4];
    const u16* xr = X + (unsigned)(r0 + lm) * 128u + lg * 8;
#pragma unroll
    for (int ks = 0; ks < 4; ++ks) {
        a0[ks] = ldfrag(xr + ks * 32);
        a1[ks] = ldfrag(xr + 16 * 128 + ks * 32);
    }
    floatx4 acc[12][2];
#pragma unroll
    for (int j = 0; j < 12; ++j) {
        acc[j][0] = floatx4{0.f, 0.f, 0.f, 0.f};
        acc[j][1] = floatx4{0.f, 0.f, 0.f, 0.f};
    }
    const u16* wbp = WIH + (nh * 192 + lm) * 128 + lg * 8;
#pragma unroll
    for (int j = 0; j < 12; ++j) {
#pragma unroll
        for (int ks = 0; ks < 4; ++ks) {
            bf16x8 bf = ldfrag(wbp + j * 2048 + ks * 32);
            acc[j][0] = MFMA(a0[ks], bf, acc[j][0]);
            acc[j][1] = MFMA(a1[ks], bf, acc[j][1]);
        }
    }
#pragma unroll
    for (int j = 0; j < 12; ++j) {
        const int col = (nh * 12 + j) * 16 + lm;
        const float bias = bih[col];
#pragma unroll
        for (int mt = 0; mt < 2; ++mt)
#pragma unroll
            for (int i = 0; i < 4; ++i) {
                unsigned row = (unsigned)(r0 + mt * 16 + lg * 4 + i);
                GI[row * 384u + col] = f2b(acc[j][mt][i] + bias);
            }
    }
}

// ---------------------------------------------------------------------------
// GRU time scan.  Block = 16 batch rows, 8 waves (512 thr); wave w owns dh
// cols [w*16, w*16+16) across all 3 gates (3 MFMA n-tiles, 12 MFMA/step).
// whh fragments loop-invariant in regs; GI prefetched one step ahead;
// h double-buffered in LDS, ONE lgkm-only barrier per step (vmem rides).
// MODE 0: write Y[b*32+t,:].  MODE 1: accumulate sum_t h -> Ssum (f32).
template <int MODE>
__global__ __launch_bounds__(512, 1) void k_scan(
    const u16* __restrict__ GI, const u16* __restrict__ WHH,
    const float* __restrict__ bhh, u16* __restrict__ Y, float* __restrict__ Ssum)
{
    __shared__ __align__(16) u16 hb[2][16][136];
    const int w = threadIdx.x >> 6, lane = threadIdx.x & 63;
    const int lm = lane & 15, lg = lane >> 4;
    const int b0 = blockIdx.x * 16;
    const int c = w * 16 + lm;                 // 0..127, this thread's h column

    bf16x8 bw[3][4];   // 3 gate n-tiles x 4 k-frags, loop-invariant
#pragma unroll
    for (int g = 0; g < 3; ++g)
#pragma unroll
        for (int ks = 0; ks < 4; ++ks)
            bw[g][ks] = ldfrag(WHH + (g * 128 + c) * 128 + ks * 32 + lg * 8);

    for (int i = threadIdx.x; i < 2 * 16 * 136; i += 512) ((u16*)hb)[i] = 0;

    const float bh0 = bhh[c], bh1 = bhh[128 + c], bh2 = bhh[256 + c];

    float hreg[4] = {}, ssum[4] = {};
    const u16* gp[4];
    u16* yp[4];
#pragma unroll
    for (int i = 0; i < 4; ++i) {
        const int row = b0 + lg * 4 + i;
        gp[i] = GI + (size_t)row * 12288 + c;
        yp[i] = (MODE == 0) ? (Y + (size_t)row * 4096 + c) : nullptr;
    }
    // prefetch t=0 (12 scalar loads with immediate gate offsets)
    u16 gvn[3][4];
#pragma unroll
    for (int i = 0; i < 4; ++i) {
        gvn[0][i] = gp[i][0];
        gvn[1][i] = gp[i][128];
        gvn[2][i] = gp[i][256];
    }
    __syncthreads();

    int cur = 0;
    for (int t = 0; t < 32; ++t) {
        bf16x8 af[4];
#pragma unroll
        for (int ks = 0; ks < 4; ++ks)
            af[ks] = ldfrag(&hb[cur][lm][ks * 32 + lg * 8]);

        // consume previous prefetch, then issue next (hides under MFMA+VALU)
        float gv[3][4];
#pragma unroll
        for (int g = 0; g < 3; ++g)
#pragma unroll
            for (int i = 0; i < 4; ++i) gv[g][i] = b2f(gvn[g][i]);
        if (t < 31) {
#pragma unroll
            for (int i = 0; i < 4; ++i) {
                gp[i] += 384;
                gvn[0][i] = gp[i][0];
                gvn[1][i] = gp[i][128];
                gvn[2][i] = gp[i][256];
            }
        }

        floatx4 acc[3];
#pragma unroll
        for (int g = 0; g < 3; ++g) acc[g] = floatx4{0.f, 0.f, 0.f, 0.f};
#pragma unroll
        for (int g = 0; g < 3; ++g)
#pragma unroll
            for (int ks = 0; ks < 4; ++ks)
                acc[g] = MFMA(af[ks], bw[g][ks], acc[g]);

        const int nxt = cur ^ 1;
#pragma unroll
        for (int i = 0; i < 4; ++i) {
            const float rr = sigm(gv[0][i] + acc[0][i] + bh0);
            const float zz = sigm(gv[1][i] + acc[1][i] + bh1);
            const float nn = tanh_(gv[2][i] + rr * (acc[2][i] + bh2));
            const float hn = (1.f - zz) * nn + zz * hreg[i];
            hreg[i] = hn;
            if (MODE == 1) ssum[i] += hn;
            const u16 hv = f2b(hn);
            hb[nxt][lg * 4 + i][c] = hv;
            if (MODE == 0) yp[i][(size_t)t * 128] = hv;
        }
        // lgkm-only barrier: h writes visible; vmem prefetch/stores ride across
        __builtin_amdgcn_sched_barrier(0);
        asm volatile("s_waitcnt lgkmcnt(0)" ::: "memory");
        __builtin_amdgcn_s_barrier();
        __builtin_amdgcn_sched_barrier(0);
        cur = nxt;
    }
    if (MODE == 1) {
#pragma unroll
        for (int i = 0; i < 4; ++i)
            Ssum[(size_t)(b0 + lg * 4 + i) * 128 + c] = ssum[i];
    }
}

// ---------------------------------------------------------------------------
// BS l1(relu, K=320) + l2(sigmoid).  M=4096 rows.
__global__ __launch_bounds__(256, 2) void k_bs_l1l2(
    const float* __restrict__ s, const float* __restrict__ a,
    const u16* __restrict__ W1T, const float* __restrict__ b1,
    const u16* __restrict__ W2T, const float* __restrict__ b2,
    u16* __restrict__ X2)
{
    __shared__ __align__(16) u16 hb[4][16][136];
    const int w = threadIdx.x >> 6, lane = threadIdx.x & 63;
    const int lm = lane & 15, lg = lane >> 4;
    const int r0 = blockIdx.x * 64 + w * 16;
    const float* srow = s + (r0 + lm) * 4352 + 4096 + lg * 8;
    const float* arow = a + (r0 + lm) * 1088 + 1024 + lg * 8;

    bf16x8 af[10];
#pragma unroll
    for (int ks = 0; ks < 8; ++ks) af[ks] = ldfrag_f32(srow + ks * 32);
    af[8] = ldfrag_f32(arow);
    af[9] = ldfrag_f32(arow + 32);

    const u16* wb1 = W1T + lm * 320 + lg * 8;
#pragma unroll
    for (int n = 0; n < 8; ++n) {
        floatx4 acc = {0.f, 0.f, 0.f, 0.f};
#pragma unroll
        for (int ks = 0; ks < 10; ++ks)
            acc = MFMA(af[ks], ldfrag(wb1 + n * 5120 + ks * 32), acc);
        const float bias = b1[n * 16 + lm];
#pragma unroll
        for (int i = 0; i < 4; ++i) {
            float x = acc[i] + bias;
            hb[w][lg * 4 + i][n * 16 + lm] = f2b(x > 0.f ? x : 0.f);
        }
    }
    __syncthreads();

    bf16x8 af2[4];
#pragma unroll
    for (int ks = 0; ks < 4; ++ks) af2[ks] = ldfrag(&hb[w][lm][ks * 32 + lg * 8]);
    const u16* wb2 = W2T + lm * 128 + lg * 8;
#pragma unroll
    for (int n = 0; n < 8; ++n) {
        floatx4 acc = {0.f, 0.f, 0.f, 0.f};
#pragma unroll
        for (int ks = 0; ks < 4; ++ks)
            acc = MFMA(af2[ks], ldfrag(wb2 + n * 2048 + ks * 32), acc);
        const float bias = b2[n * 16 + lm];
#pragma unroll
        for (int i = 0; i < 4; ++i) {
            float v = sigm(acc[i] + bias);
            X2[(unsigned)(r0 + lg * 4 + i) * 128u + n * 16 + lm] = f2b(v);
        }
    }
}

// ---------------------------------------------------------------------------
// BS GRU single step with h_prev = 0 (true for both layers at T=1):
// h = (1-z)*tanh(gi_n + bih_n + r*bhh_n), r/z = sigm(gi + bih + bhh).
template <int OUTF32>
__global__ __launch_bounds__(256, 2) void k_bs_gru(
    const u16* __restrict__ X, const u16* __restrict__ WIH,
    const float* __restrict__ bih, const float* __restrict__ bhh,
    u16* __restrict__ Hb, float* __restrict__ Hf)
{
    const int w = threadIdx.x >> 6, lane = threadIdx.x & 63;
    const int lm = lane & 15, lg = lane >> 4;
    const int r0 = blockIdx.x * 64 + w * 16;

    bf16x8 ax[4];
    const u16* xr = X + (unsigned)(r0 + lm) * 128u + lg * 8;
#pragma unroll
    for (int ks = 0; ks < 4; ++ks) ax[ks] = ldfrag(xr + ks * 32);

    floatx4 acc[24];  // j<8: r-gate cols, 8..15: z, 16..23: n
#pragma unroll
    for (int j = 0; j < 24; ++j) acc[j] = floatx4{0.f, 0.f, 0.f, 0.f};
    const u16* wbp = WIH + lm * 128 + lg * 8;
#pragma unroll
    for (int j = 0; j < 24; ++j)
#pragma unroll
        for (int ks = 0; ks < 4; ++ks)
            acc[j] = MFMA(ax[ks], ldfrag(wbp + j * 2048 + ks * 32), acc[j]);

#pragma unroll
    for (int ct = 0; ct < 8; ++ct) {
        const int c = ct * 16 + lm;
        const float br = bih[c] + bhh[c];
        const float bz = bih[128 + c] + bhh[128 + c];
        const float bni = bih[256 + c], bnh = bhh[256 + c];
#pragma unroll
        for (int i = 0; i < 4; ++i) {
            const float rr = sigm(acc[ct][i] + br);
            const float zz = sigm(acc[8 + ct][i] + bz);
            const float nn = tanh_(acc[16 + ct][i] + bni + rr * bnh);
            const float h = (1.f - zz) * nn;
            const unsigned row = (unsigned)(r0 + lg * 4 + i);
            if (OUTF32) Hf[row * 128u + c] = h;
            else        Hb[row * 128u + c] = f2b(h);
        }
    }
}

// ---------------------------------------------------------------------------
// Final: S = SSUM + HBS;  out = relu(elu(S@gat_w) @ ev1 + b1) @ ev2 + b2.
__global__ __launch_bounds__(256, 2) void k_final(
    const float* __restrict__ Ssum, const float* __restrict__ HBS,
    const u16* __restrict__ GATWT, const u16* __restrict__ EV1T,
    const float* __restrict__ ev1b, const float* __restrict__ ev2w,
    const float* __restrict__ ev2b, float* __restrict__ out)
{
    __shared__ __align__(16) u16 hb[4][16][136];
    __shared__ float xb[4][16][132];
    const int w = threadIdx.x >> 6, lane = threadIdx.x & 63;
    const int lm = lane & 15, lg = lane >> 4;
    const int r0 = blockIdx.x * 64 + w * 16;

    const float* p1 = Ssum + (unsigned)(r0 + lm) * 128u + lg * 8;
    const float* p2 = HBS  + (unsigned)(r0 + lm) * 128u + lg * 8;
    bf16x8 af[4];
#pragma unroll
    for (int ks = 0; ks < 4; ++ks) {
        float4 u = *reinterpret_cast<const float4*>(p1 + ks * 32);
        float4 u2 = *reinterpret_cast<const float4*>(p1 + ks * 32 + 4);
        float4 v = *reinterpret_cast<const float4*>(p2 + ks * 32);
        float4 v2 = *reinterpret_cast<const float4*>(p2 + ks * 32 + 4);
        short8 pk;
        pk[0] = (short)f2b(u.x + v.x); pk[1] = (short)f2b(u.y + v.y);
        pk[2] = (short)f2b(u.z + v.z); pk[3] = (short)f2b(u.w + v.w);
        pk[4] = (short)f2b(u2.x + v2.x); pk[5] = (short)f2b(u2.y + v2.y);
        pk[6] = (short)f2b(u2.z + v2.z); pk[7] = (short)f2b(u2.w + v2.w);
        af[ks] = __builtin_bit_cast(bf16x8, pk);
    }
    const u16* gwp = GATWT + lm * 128 + lg * 8;
#pragma unroll
    for (int n = 0; n < 8; ++n) {
        floatx4 acc = {0.f, 0.f, 0.f, 0.f};
#pragma unroll
        for (int ks = 0; ks < 4; ++ks)
            acc = MFMA(af[ks], ldfrag(gwp + n * 2048 + ks * 32), acc);
#pragma unroll
        for (int i = 0; i < 4; ++i) {
            float x = acc[i];
            x = x > 0.f ? x : (__expf(x) - 1.f);            // elu
            hb[w][lg * 4 + i][n * 16 + lm] = f2b(x);
        }
    }
    __syncthreads();

    bf16x8 af2[4];
#pragma unroll
    for (int ks = 0; ks < 4; ++ks) af2[ks] = ldfrag(&hb[w][lm][ks * 32 + lg * 8]);
    const u16* e1p = EV1T + lm * 128 + lg * 8;
#pragma unroll
    for (int n = 0; n < 8; ++n) {
        floatx4 acc = {0.f, 0.f, 0.f, 0.f};
#pragma unroll
        for (int ks = 0; ks < 4; ++ks)
            acc = MFMA(af2[ks], ldfrag(e1p + n * 2048 + ks * 32), acc);
        const float bias = ev1b[n * 16 + lm];
#pragma unroll
        for (int i = 0; i < 4; ++i) {
            float v = acc[i] + bias;
            xb[w][lg * 4 + i][n * 16 + lm] = v > 0.f ? v : 0.f;  // relu
        }
    }
    __syncthreads();

    float sacc = 0.f;
#pragma unroll
    for (int k = 0; k < 32; ++k) {
        const int c = lg * 32 + k;
        sacc += xb[w][lm][c] * ev2w[c];
    }
    sacc += __shfl_xor(sacc, 16, 64);
    sacc += __shfl_xor(sacc, 32, 64);
    if (lg == 0) out[r0 + lm] = sacc + ev2b[0];
}

// ---------------------------------------------------------------------------
extern "C" void kernel_launch(void* const* d_in, const int* in_sizes, int n_in,
                              void* d_out, int out_size, void* d_ws, size_t ws_size,
                              hipStream_t stream)
{
    (void)in_sizes; (void)n_in; (void)out_size; (void)ws_size;
    const float* s       = (const float*)d_in[0];
    const float* a       = (const float*)d_in[1];
    const float* ue_l1_w = (const float*)d_in[2];
    const float* ue_l1_b = (const float*)d_in[3];
    const float* ue_l2_w = (const float*)d_in[4];
    const float* ue_l2_b = (const float*)d_in[5];
    const float* ue_wih0 = (const float*)d_in[6];
    const float* ue_whh0 = (const float*)d_in[7];
    const float* ue_bih0 = (const float*)d_in[8];
    const float* ue_bhh0 = (const float*)d_in[9];
    const float* ue_wih1 = (const float*)d_in[10];
    const float* ue_whh1 = (const float*)d_in[11];
    const float* ue_bih1 = (const float*)d_in[12];
    const float* ue_bhh1 = (const float*)d_in[13];
    const float* bs_l1_w = (const float*)d_in[14];
    const float* bs_l1_b = (const float*)d_in[15];
    const float* bs_l2_w = (const float*)d_in[16];
    const float* bs_l2_b = (const float*)d_in[17];
    const float* bs_wih0 = (const float*)d_in[18];
    const float* bs_bih0 = (const float*)d_in[20];
    const float* bs_bhh0 = (const float*)d_in[21];
    const float* bs_wih1 = (const float*)d_in[22];
    const float* bs_bih1 = (const float*)d_in[24];
    const float* bs_bhh1 = (const float*)d_in[25];
    const float* gat_w   = (const float*)d_in[26];
    const float* ev1_w   = (const float*)d_in[29];
    const float* ev1_b   = (const float*)d_in[30];
    const float* ev2_w   = (const float*)d_in[31];
    const float* ev2_b   = (const float*)d_in[32];

    char* ws = (char*)d_ws;
    u16*   wb   = (u16*)ws;
    u16*   X2   = (u16*)(ws + WB_X2);
    u16*   GI   = (u16*)(ws + WB_GI);
    u16*   X2BS = (u16*)(ws + WB_X2BS);
    u16*   H0BS = (u16*)(ws + WB_H0BS);
    float* HBS  = (float*)(ws + WB_HBS);
    float* SSUM = (float*)(ws + WB_SSUM);

    k_prep<<<256, 256, 0, stream>>>(ue_l1_w, ue_l2_w, ue_wih0, ue_whh0,
                                    ue_wih1, ue_whh1, bs_l1_w, bs_l2_w,
                                    bs_wih0, bs_wih1, gat_w, ev1_w, wb);
    k_ue_l1l2<<<2048, 256, 0, stream>>>(s, a, wb + O_UE_W1T, ue_l1_b,
                                        wb + O_UE_W2T, ue_l2_b, X2);
    k_gi<<<2048, 256, 0, stream>>>(X2, wb + O_UE_WIH0, ue_bih0, GI);
    k_scan<0><<<256, 512, 0, stream>>>(GI, wb + O_UE_WHH0, ue_bhh0, X2, nullptr);
    k_gi<<<2048, 256, 0, stream>>>(X2, wb + O_UE_WIH1, ue_bih1, GI);
    k_scan<1><<<256, 512, 0, stream>>>(GI, wb + O_UE_WHH1, ue_bhh1, nullptr, SSUM);
    k_bs_l1l2<<<64, 256, 0, stream>>>(s, a, wb + O_BS_W1T, bs_l1_b,
                                      wb + O_BS_W2T, bs_l2_b, X2BS);
    k_bs_gru<0><<<64, 256, 0, stream>>>(X2BS, wb + O_BS_WIH0, bs_bih0, bs_bhh0,
                                        H0BS, nullptr);
    k_bs_gru<1><<<64, 256, 0, stream>>>(H0BS, wb + O_BS_WIH1, bs_bih1, bs_bhh1,
                                        nullptr, HBS);
    k_final<<<64, 256, 0, stream>>>(SSUM, HBS, wb + O_GATWT, wb + O_EV1T,
                                    ev1_b, ev2_w, ev2_b, (float*)d_out);
}

// Round 3
// 370.632 us; speedup vs baseline: 1.6736x; 1.4615x over previous
//
#include <hip/hip_runtime.h>

// ---------------------------------------------------------------------------
// HetGAT critic on MI355X (gfx950), bf16-MFMA implementation.
//
// Algebraic simplification: softmax(axis=1) + einsum('bij,bjf->bf') makes the
// attention sum to exactly 1 per column => h_prime = (sum_nodes emb) @ gat_w.
// gat_a / adj / leaky_relu / softmax are dead code.
//
// Round-2 structure:
//  * k_ue_l1l2: 512thr/128rows; s,a staged once into LDS (bf16); wave w owns
//    n-tile w with weight frags loop-invariant in regs (no per-row reloads).
//  * GI GEMM fused INTO the scan (k_gi deleted): per step, gi = x_t@Wih^T is
//    computed from register-prefetched x_t (independent of h => overlaps the
//    h ds_read + barrier), then h-MFMAs. Saves 200MB of GI round-trip.
//  * scan keeps: 8 waves x 16 cols, Whh/Wih frags in regs, h double-buffered
//    in LDS, ONE lgkm-only barrier per step (vmem rides across).
// BS branch: T=1, h0=0 => gh == bhh (whh unused).
//
// MFMA v_mfma_f32_16x16x32_bf16 layouts:
//   A[m][k]: m=lane&15, k=(lane>>4)*8+i   (8 contiguous bf16 per lane)
//   B[k][n]: n=lane&15, k=(lane>>4)*8+i   (weights stored transposed [N][K])
//   D[m][n]: n=lane&15, m=(lane>>4)*4+reg
// ---------------------------------------------------------------------------

typedef unsigned short u16;
typedef __bf16  bf16x8  __attribute__((ext_vector_type(8)));
typedef short   short8  __attribute__((ext_vector_type(8)));
typedef u16     u16x4   __attribute__((ext_vector_type(4)));
typedef float   floatx4 __attribute__((ext_vector_type(4)));

#define DEVI __device__ __forceinline__
#define MFMA(a, b, c) __builtin_amdgcn_mfma_f32_16x16x32_bf16((a), (b), (c), 0, 0, 0)

DEVI u16 f2b(float f) {                       // f32 -> bf16 bits, RNE
    unsigned u = __float_as_uint(f);
    u += 0x7fffu + ((u >> 16) & 1u);
    return (u16)(u >> 16);
}
DEVI float b2f(u16 s) { return __uint_as_float(((unsigned)s) << 16); }
DEVI float sigm(float x) { return 1.f / (1.f + __expf(-x)); }
DEVI float tanh_(float x) { return 1.f - 2.f / (__expf(2.f * x) + 1.f); }

DEVI bf16x8 ldfrag(const u16* q) {            // 8 contiguous bf16 (16B aligned)
    return *reinterpret_cast<const bf16x8*>(q);
}
DEVI bf16x8 ldfrag_f32(const float* q) {      // 8 contiguous f32 -> bf16 frag
    float4 u = *reinterpret_cast<const float4*>(q);
    float4 v = *reinterpret_cast<const float4*>(q + 4);
    short8 pk;
    pk[0] = (short)f2b(u.x); pk[1] = (short)f2b(u.y);
    pk[2] = (short)f2b(u.z); pk[3] = (short)f2b(u.w);
    pk[4] = (short)f2b(v.x); pk[5] = (short)f2b(v.y);
    pk[6] = (short)f2b(v.z); pk[7] = (short)f2b(v.w);
    return __builtin_bit_cast(bf16x8, pk);
}

// bf16 weight offsets inside ws (elements)
enum : int {
    O_UE_W1T  = 0,        // [128][160]
    O_UE_W2T  = 20480,    // [128][128]
    O_UE_WIH0 = 36864,    // [384][128]
    O_UE_WHH0 = 86016,
    O_UE_WIH1 = 135168,
    O_UE_WHH1 = 184320,
    O_BS_W1T  = 233472,   // [128][320]
    O_BS_W2T  = 274432,
    O_BS_WIH0 = 290816,
    O_BS_WIH1 = 339968,
    O_GATWT   = 389120,   // [128][128]
    O_EV1T    = 405504,   // [128][128]
};
// ws byte offsets
#define WB_X2   1048576u
#define WB_Y0   34603008u
#define WB_X2BS 135266304u
#define WB_H0BS 136314880u
#define WB_HBS  137363456u
#define WB_SSUM 139460608u

// ---------------------------------------------------------------------------
__global__ __launch_bounds__(256) void k_prep(
    const float* __restrict__ ue1, const float* __restrict__ ue2,
    const float* __restrict__ uw0, const float* __restrict__ uh0,
    const float* __restrict__ uw1, const float* __restrict__ uh1,
    const float* __restrict__ bs1, const float* __restrict__ bs2,
    const float* __restrict__ bw0, const float* __restrict__ bw1,
    const float* __restrict__ gw,  const float* __restrict__ e1,
    u16* __restrict__ out)
{
    const int tid = blockIdx.x * blockDim.x + threadIdx.x;
    const int stride = gridDim.x * blockDim.x;
    auto cvt = [&](const float* s, int off, int n) {
        for (int i = tid; i < n; i += stride) out[off + i] = f2b(s[i]);
    };
    auto tcv = [&](const float* s, int off, int K, int N) {  // [K,N] -> [N,K]
        const int tot = K * N;
        for (int i = tid; i < tot; i += stride) {
            int nn = i / K, kk = i - nn * K;
            out[off + i] = f2b(s[kk * N + nn]);
        }
    };
    tcv(ue1, O_UE_W1T, 160, 128);  tcv(ue2, O_UE_W2T, 128, 128);
    cvt(uw0, O_UE_WIH0, 49152);    cvt(uh0, O_UE_WHH0, 49152);
    cvt(uw1, O_UE_WIH1, 49152);    cvt(uh1, O_UE_WHH1, 49152);
    tcv(bs1, O_BS_W1T, 320, 128);  tcv(bs2, O_BS_W2T, 128, 128);
    cvt(bw0, O_BS_WIH0, 49152);    cvt(bw1, O_BS_WIH1, 49152);
    tcv(gw,  O_GATWT, 128, 128);   tcv(e1,  O_EV1T, 128, 128);
}

// ---------------------------------------------------------------------------
// UE l1(relu) + l2(sigmoid), fused.  512 thr, 128 rows/block, grid 1024.
// s,a staged once into LDS as bf16; wave w owns output n-tile w with l1/l2
// weight fragments held loop-invariant in registers.
__global__ __launch_bounds__(512, 2) void k_ue_l1l2(
    const float* __restrict__ s, const float* __restrict__ a,
    const u16* __restrict__ W1T, const float* __restrict__ b1,
    const u16* __restrict__ W2T, const float* __restrict__ b2,
    u16* __restrict__ X2)
{
    __shared__ __align__(16) u16 A1[128][168];   // 160 cols + pad (336B stride)
    __shared__ __align__(16) u16 H[128][136];    // 128 cols + pad (272B stride)
    const int tid = threadIdx.x;
    const int w = tid >> 6, lane = tid & 63;
    const int lm = lane & 15, lg = lane >> 4;
    const int r0 = blockIdx.x * 128;

    // wave-invariant weight fragments (issued before staging; overlap)
    bf16x8 bw1[5], bw2[4];
#pragma unroll
    for (int ks = 0; ks < 5; ++ks)
        bw1[ks] = ldfrag(W1T + (w * 16 + lm) * 160 + ks * 32 + lg * 8);
#pragma unroll
    for (int ks = 0; ks < 4; ++ks)
        bw2[ks] = ldfrag(W2T + (w * 16 + lm) * 128 + ks * 32 + lg * 8);
    const float bias1 = b1[w * 16 + lm];
    const float bias2 = b2[w * 16 + lm];

    // stage s rows (128 rows x 32 float4), coalesced
#pragma unroll
    for (int it = 0; it < 8; ++it) {
        const int fidx = it * 512 + tid;
        const int row = fidx >> 5, c4 = fidx & 31;
        const int r = r0 + row, bb = r >> 5, tt = r & 31;
        float4 v = *reinterpret_cast<const float4*>(s + (size_t)bb * 4352 + tt * 128 + c4 * 4);
        u16x4 p = {f2b(v.x), f2b(v.y), f2b(v.z), f2b(v.w)};
        *reinterpret_cast<u16x4*>(&A1[row][c4 * 4]) = p;
    }
    // stage a rows (128 rows x 8 float4)
#pragma unroll
    for (int it = 0; it < 2; ++it) {
        const int fidx = it * 512 + tid;
        const int row = fidx >> 3, c4 = fidx & 7;
        const int r = r0 + row, bb = r >> 5, tt = r & 31;
        float4 v = *reinterpret_cast<const float4*>(a + (size_t)bb * 1088 + tt * 32 + c4 * 4);
        u16x4 p = {f2b(v.x), f2b(v.y), f2b(v.z), f2b(v.w)};
        *reinterpret_cast<u16x4*>(&A1[row][128 + c4 * 4]) = p;
    }
    __syncthreads();

    // l1: relu -> H
#pragma unroll
    for (int mt = 0; mt < 8; ++mt) {
        bf16x8 af[5];
#pragma unroll
        for (int ks = 0; ks < 5; ++ks)
            af[ks] = ldfrag(&A1[mt * 16 + lm][ks * 32 + lg * 8]);
        floatx4 acc = {0.f, 0.f, 0.f, 0.f};
#pragma unroll
        for (int ks = 0; ks < 5; ++ks) acc = MFMA(af[ks], bw1[ks], acc);
#pragma unroll
        for (int i = 0; i < 4; ++i) {
            float x = acc[i] + bias1;
            H[mt * 16 + lg * 4 + i][w * 16 + lm] = f2b(x > 0.f ? x : 0.f);
        }
    }
    __syncthreads();

    // l2: sigmoid -> X2
#pragma unroll
    for (int mt = 0; mt < 8; ++mt) {
        bf16x8 af[4];
#pragma unroll
        for (int ks = 0; ks < 4; ++ks)
            af[ks] = ldfrag(&H[mt * 16 + lm][ks * 32 + lg * 8]);
        floatx4 acc = {0.f, 0.f, 0.f, 0.f};
#pragma unroll
        for (int ks = 0; ks < 4; ++ks) acc = MFMA(af[ks], bw2[ks], acc);
#pragma unroll
        for (int i = 0; i < 4; ++i)
            X2[(size_t)(r0 + mt * 16 + lg * 4 + i) * 128 + w * 16 + lm] =
                f2b(sigm(acc[i] + bias2));
    }
}

// ---------------------------------------------------------------------------
// Fused GRU layer: gi GEMM + time scan in one kernel.
// Block = 16 batch rows, 8 waves (512 thr); wave w owns dh cols
// [w*16,w*16+16) across all 3 gates.  Wih/Whh frags loop-invariant in regs;
// x_t prefetched one step ahead into regs (independent of h => overlaps the
// h ds_read + barrier); h double-buffered in LDS, one lgkm-only barrier/step.
// MODE 0: write h_t to Y[b*32+t,:].  MODE 1: accumulate sum_t h -> Ssum.
template <int MODE>
__global__ __launch_bounds__(512, 2) void k_scan(
    const u16* __restrict__ X, const u16* __restrict__ WIH,
    const u16* __restrict__ WHH,
    const float* __restrict__ bih, const float* __restrict__ bhh,
    u16* __restrict__ Y, float* __restrict__ Ssum)
{
    __shared__ __align__(16) u16 hb[2][16][136];
    const int w = threadIdx.x >> 6, lane = threadIdx.x & 63;
    const int lm = lane & 15, lg = lane >> 4;
    const int b0 = blockIdx.x * 16;
    const int c = w * 16 + lm;                 // this thread's h column

    bf16x8 bwh[3][4], bwi[3][4];   // Whh / Wih frags, loop-invariant
#pragma unroll
    for (int g = 0; g < 3; ++g)
#pragma unroll
        for (int ks = 0; ks < 4; ++ks) {
            bwh[g][ks] = ldfrag(WHH + (g * 128 + c) * 128 + ks * 32 + lg * 8);
            bwi[g][ks] = ldfrag(WIH + (g * 128 + c) * 128 + ks * 32 + lg * 8);
        }

    for (int i = threadIdx.x; i < 2 * 16 * 136; i += 512) ((u16*)hb)[i] = 0;

    const float br  = bih[c] + bhh[c];
    const float bz  = bih[128 + c] + bhh[128 + c];
    const float bni = bih[256 + c], bnh = bhh[256 + c];

    // per-lane x A-frag pointer: batch row b0+lm, k-group lg
    const u16* xp = X + (size_t)(b0 + lm) * 32 * 128 + lg * 8;
    bf16x8 xa[4], xn[4];
#pragma unroll
    for (int ks = 0; ks < 4; ++ks) xa[ks] = ldfrag(xp + ks * 32);   // t=0

    float hreg[4] = {}, ssum[4] = {};
    __syncthreads();

    int cur = 0;
    for (int t = 0; t < 32; ++t) {
        // h frags (lgkm in flight while gi MFMAs run)
        bf16x8 af[4];
#pragma unroll
        for (int ks = 0; ks < 4; ++ks)
            af[ks] = ldfrag(&hb[cur][lm][ks * 32 + lg * 8]);

        // gi = x_t @ Wih^T  (x in regs: ready immediately)
        floatx4 gacc[3];
#pragma unroll
        for (int g = 0; g < 3; ++g) gacc[g] = floatx4{0.f, 0.f, 0.f, 0.f};
#pragma unroll
        for (int g = 0; g < 3; ++g)
#pragma unroll
            for (int ks = 0; ks < 4; ++ks)
                gacc[g] = MFMA(xa[ks], bwi[g][ks], gacc[g]);

        // prefetch x_{t+1}
        if (t < 31) {
#pragma unroll
            for (int ks = 0; ks < 4; ++ks)
                xn[ks] = ldfrag(xp + (t + 1) * 128 + ks * 32);
        }

        // gh = h_t @ Whh^T
        floatx4 hacc[3];
#pragma unroll
        for (int g = 0; g < 3; ++g) hacc[g] = floatx4{0.f, 0.f, 0.f, 0.f};
#pragma unroll
        for (int g = 0; g < 3; ++g)
#pragma unroll
            for (int ks = 0; ks < 4; ++ks)
                hacc[g] = MFMA(af[ks], bwh[g][ks], hacc[g]);

        const int nxt = cur ^ 1;
#pragma unroll
        for (int i = 0; i < 4; ++i) {
            const float rr = sigm(gacc[0][i] + hacc[0][i] + br);
            const float zz = sigm(gacc[1][i] + hacc[1][i] + bz);
            const float nn = tanh_(gacc[2][i] + bni + rr * (hacc[2][i] + bnh));
            const float hn = (1.f - zz) * nn + zz * hreg[i];
            hreg[i] = hn;
            if (MODE == 1) ssum[i] += hn;
            const u16 hv = f2b(hn);
            hb[nxt][lg * 4 + i][c] = hv;
            if (MODE == 0)
                Y[((size_t)(b0 + lg * 4 + i) * 32 + t) * 128 + c] = hv;
        }
#pragma unroll
        for (int ks = 0; ks < 4; ++ks) xa[ks] = xn[ks];

        // lgkm-only barrier: h writes visible; vmem prefetch/stores ride across
        __builtin_amdgcn_sched_barrier(0);
        asm volatile("s_waitcnt lgkmcnt(0)" ::: "memory");
        __builtin_amdgcn_s_barrier();
        __builtin_amdgcn_sched_barrier(0);
        cur = nxt;
    }
    if (MODE == 1) {
#pragma unroll
        for (int i = 0; i < 4; ++i)
            Ssum[(size_t)(b0 + lg * 4 + i) * 128 + c] = ssum[i];
    }
}

// ---------------------------------------------------------------------------
// BS l1(relu, K=320) + l2(sigmoid).  M=4096 rows.
__global__ __launch_bounds__(256, 2) void k_bs_l1l2(
    const float* __restrict__ s, const float* __restrict__ a,
    const u16* __restrict__ W1T, const float* __restrict__ b1,
    const u16* __restrict__ W2T, const float* __restrict__ b2,
    u16* __restrict__ X2)
{
    __shared__ __align__(16) u16 hb[4][16][136];
    const int w = threadIdx.x >> 6, lane = threadIdx.x & 63;
    const int lm = lane & 15, lg = lane >> 4;
    const int r0 = blockIdx.x * 64 + w * 16;
    const float* srow = s + (size_t)(r0 + lm) * 4352 + 4096 + lg * 8;
    const float* arow = a + (size_t)(r0 + lm) * 1088 + 1024 + lg * 8;

    bf16x8 af[10];
#pragma unroll
    for (int ks = 0; ks < 8; ++ks) af[ks] = ldfrag_f32(srow + ks * 32);
    af[8] = ldfrag_f32(arow);
    af[9] = ldfrag_f32(arow + 32);

    const u16* wb1 = W1T + lm * 320 + lg * 8;
#pragma unroll
    for (int n = 0; n < 8; ++n) {
        floatx4 acc = {0.f, 0.f, 0.f, 0.f};
#pragma unroll
        for (int ks = 0; ks < 10; ++ks)
            acc = MFMA(af[ks], ldfrag(wb1 + n * 5120 + ks * 32), acc);
        const float bias = b1[n * 16 + lm];
#pragma unroll
        for (int i = 0; i < 4; ++i) {
            float x = acc[i] + bias;
            hb[w][lg * 4 + i][n * 16 + lm] = f2b(x > 0.f ? x : 0.f);
        }
    }
    __syncthreads();

    bf16x8 af2[4];
#pragma unroll
    for (int ks = 0; ks < 4; ++ks) af2[ks] = ldfrag(&hb[w][lm][ks * 32 + lg * 8]);
    const u16* wb2 = W2T + lm * 128 + lg * 8;
#pragma unroll
    for (int n = 0; n < 8; ++n) {
        floatx4 acc = {0.f, 0.f, 0.f, 0.f};
#pragma unroll
        for (int ks = 0; ks < 4; ++ks)
            acc = MFMA(af2[ks], ldfrag(wb2 + n * 2048 + ks * 32), acc);
        const float bias = b2[n * 16 + lm];
#pragma unroll
        for (int i = 0; i < 4; ++i) {
            float v = sigm(acc[i] + bias);
            X2[(unsigned)(r0 + lg * 4 + i) * 128u + n * 16 + lm] = f2b(v);
        }
    }
}

// ---------------------------------------------------------------------------
// BS GRU single step with h_prev = 0 (true for both layers at T=1):
// h = (1-z)*tanh(gi_n + bih_n + r*bhh_n), r/z = sigm(gi + bih + bhh).
template <int OUTF32>
__global__ __launch_bounds__(256, 2) void k_bs_gru(
    const u16* __restrict__ X, const u16* __restrict__ WIH,
    const float* __restrict__ bih, const float* __restrict__ bhh,
    u16* __restrict__ Hb, float* __restrict__ Hf)
{
    const int w = threadIdx.x >> 6, lane = threadIdx.x & 63;
    const int lm = lane & 15, lg = lane >> 4;
    const int r0 = blockIdx.x * 64 + w * 16;

    bf16x8 ax[4];
    const u16* xr = X + (unsigned)(r0 + lm) * 128u + lg * 8;
#pragma unroll
    for (int ks = 0; ks < 4; ++ks) ax[ks] = ldfrag(xr + ks * 32);

    floatx4 acc[24];  // j<8: r-gate cols, 8..15: z, 16..23: n
#pragma unroll
    for (int j = 0; j < 24; ++j) acc[j] = floatx4{0.f, 0.f, 0.f, 0.f};
    const u16* wbp = WIH + lm * 128 + lg * 8;
#pragma unroll
    for (int j = 0; j < 24; ++j)
#pragma unroll
        for (int ks = 0; ks < 4; ++ks)
            acc[j] = MFMA(ax[ks], ldfrag(wbp + j * 2048 + ks * 32), acc[j]);

#pragma unroll
    for (int ct = 0; ct < 8; ++ct) {
        const int c = ct * 16 + lm;
        const float br = bih[c] + bhh[c];
        const float bz = bih[128 + c] + bhh[128 + c];
        const float bni = bih[256 + c], bnh = bhh[256 + c];
#pragma unroll
        for (int i = 0; i < 4; ++i) {
            const float rr = sigm(acc[ct][i] + br);
            const float zz = sigm(acc[8 + ct][i] + bz);
            const float nn = tanh_(acc[16 + ct][i] + bni + rr * bnh);
            const float h = (1.f - zz) * nn;
            const unsigned row = (unsigned)(r0 + lg * 4 + i);
            if (OUTF32) Hf[row * 128u + c] = h;
            else        Hb[row * 128u + c] = f2b(h);
        }
    }
}

// ---------------------------------------------------------------------------
// Final: S = SSUM + HBS;  out = relu(elu(S@gat_w) @ ev1 + b1) @ ev2 + b2.
__global__ __launch_bounds__(256, 2) void k_final(
    const float* __restrict__ Ssum, const float* __restrict__ HBS,
    const u16* __restrict__ GATWT, const u16* __restrict__ EV1T,
    const float* __restrict__ ev1b, const float* __restrict__ ev2w,
    const float* __restrict__ ev2b, float* __restrict__ out)
{
    __shared__ __align__(16) u16 hb[4][16][136];
    __shared__ float xb[4][16][132];
    const int w = threadIdx.x >> 6, lane = threadIdx.x & 63;
    const int lm = lane & 15, lg = lane >> 4;
    const int r0 = blockIdx.x * 64 + w * 16;

    const float* p1 = Ssum + (unsigned)(r0 + lm) * 128u + lg * 8;
    const float* p2 = HBS  + (unsigned)(r0 + lm) * 128u + lg * 8;
    bf16x8 af[4];
#pragma unroll
    for (int ks = 0; ks < 4; ++ks) {
        float4 u = *reinterpret_cast<const float4*>(p1 + ks * 32);
        float4 u2 = *reinterpret_cast<const float4*>(p1 + ks * 32 + 4);
        float4 v = *reinterpret_cast<const float4*>(p2 + ks * 32);
        float4 v2 = *reinterpret_cast<const float4*>(p2 + ks * 32 + 4);
        short8 pk;
        pk[0] = (short)f2b(u.x + v.x); pk[1] = (short)f2b(u.y + v.y);
        pk[2] = (short)f2b(u.z + v.z); pk[3] = (short)f2b(u.w + v.w);
        pk[4] = (short)f2b(u2.x + v2.x); pk[5] = (short)f2b(u2.y + v2.y);
        pk[6] = (short)f2b(u2.z + v2.z); pk[7] = (short)f2b(u2.w + v2.w);
        af[ks] = __builtin_bit_cast(bf16x8, pk);
    }
    const u16* gwp = GATWT + lm * 128 + lg * 8;
#pragma unroll
    for (int n = 0; n < 8; ++n) {
        floatx4 acc = {0.f, 0.f, 0.f, 0.f};
#pragma unroll
        for (int ks = 0; ks < 4; ++ks)
            acc = MFMA(af[ks], ldfrag(gwp + n * 2048 + ks * 32), acc);
#pragma unroll
        for (int i = 0; i < 4; ++i) {
            float x = acc[i];
            x = x > 0.f ? x : (__expf(x) - 1.f);            // elu
            hb[w][lg * 4 + i][n * 16 + lm] = f2b(x);
        }
    }
    __syncthreads();

    bf16x8 af2[4];
#pragma unroll
    for (int ks = 0; ks < 4; ++ks) af2[ks] = ldfrag(&hb[w][lm][ks * 32 + lg * 8]);
    const u16* e1p = EV1T + lm * 128 + lg * 8;
#pragma unroll
    for (int n = 0; n < 8; ++n) {
        floatx4 acc = {0.f, 0.f, 0.f, 0.f};
#pragma unroll
        for (int ks = 0; ks < 4; ++ks)
            acc = MFMA(af2[ks], ldfrag(e1p + n * 2048 + ks * 32), acc);
        const float bias = ev1b[n * 16 + lm];
#pragma unroll
        for (int i = 0; i < 4; ++i) {
            float v = acc[i] + bias;
            xb[w][lg * 4 + i][n * 16 + lm] = v > 0.f ? v : 0.f;  // relu
        }
    }
    __syncthreads();

    float sacc = 0.f;
#pragma unroll
    for (int k = 0; k < 32; ++k) {
        const int c = lg * 32 + k;
        sacc += xb[w][lm][c] * ev2w[c];
    }
    sacc += __shfl_xor(sacc, 16, 64);
    sacc += __shfl_xor(sacc, 32, 64);
    if (lg == 0) out[r0 + lm] = sacc + ev2b[0];
}

// ---------------------------------------------------------------------------
extern "C" void kernel_launch(void* const* d_in, const int* in_sizes, int n_in,
                              void* d_out, int out_size, void* d_ws, size_t ws_size,
                              hipStream_t stream)
{
    (void)in_sizes; (void)n_in; (void)out_size; (void)ws_size;
    const float* s       = (const float*)d_in[0];
    const float* a       = (const float*)d_in[1];
    const float* ue_l1_w = (const float*)d_in[2];
    const float* ue_l1_b = (const float*)d_in[3];
    const float* ue_l2_w = (const float*)d_in[4];
    const float* ue_l2_b = (const float*)d_in[5];
    const float* ue_wih0 = (const float*)d_in[6];
    const float* ue_whh0 = (const float*)d_in[7];
    const float* ue_bih0 = (const float*)d_in[8];
    const float* ue_bhh0 = (const float*)d_in[9];
    const float* ue_wih1 = (const float*)d_in[10];
    const float* ue_whh1 = (const float*)d_in[11];
    const float* ue_bih1 = (const float*)d_in[12];
    const float* ue_bhh1 = (const float*)d_in[13];
    const float* bs_l1_w = (const float*)d_in[14];
    const float* bs_l1_b = (const float*)d_in[15];
    const float* bs_l2_w = (const float*)d_in[16];
    const float* bs_l2_b = (const float*)d_in[17];
    const float* bs_wih0 = (const float*)d_in[18];
    const float* bs_bih0 = (const float*)d_in[20];
    const float* bs_bhh0 = (const float*)d_in[21];
    const float* bs_wih1 = (const float*)d_in[22];
    const float* bs_bih1 = (const float*)d_in[24];
    const float* bs_bhh1 = (const float*)d_in[25];
    const float* gat_w   = (const float*)d_in[26];
    const float* ev1_w   = (const float*)d_in[29];
    const float* ev1_b   = (const float*)d_in[30];
    const float* ev2_w   = (const float*)d_in[31];
    const float* ev2_b   = (const float*)d_in[32];

    char* ws = (char*)d_ws;
    u16*   wb   = (u16*)ws;
    u16*   X2   = (u16*)(ws + WB_X2);
    u16*   Y0   = (u16*)(ws + WB_Y0);
    u16*   X2BS = (u16*)(ws + WB_X2BS);
    u16*   H0BS = (u16*)(ws + WB_H0BS);
    float* HBS  = (float*)(ws + WB_HBS);
    float* SSUM = (float*)(ws + WB_SSUM);

    k_prep<<<256, 256, 0, stream>>>(ue_l1_w, ue_l2_w, ue_wih0, ue_whh0,
                                    ue_wih1, ue_whh1, bs_l1_w, bs_l2_w,
                                    bs_wih0, bs_wih1, gat_w, ev1_w, wb);
    k_ue_l1l2<<<1024, 512, 0, stream>>>(s, a, wb + O_UE_W1T, ue_l1_b,
                                        wb + O_UE_W2T, ue_l2_b, X2);
    k_scan<0><<<256, 512, 0, stream>>>(X2, wb + O_UE_WIH0, wb + O_UE_WHH0,
                                       ue_bih0, ue_bhh0, Y0, nullptr);
    k_scan<1><<<256, 512, 0, stream>>>(Y0, wb + O_UE_WIH1, wb + O_UE_WHH1,
                                       ue_bih1, ue_bhh1, nullptr, SSUM);
    k_bs_l1l2<<<64, 256, 0, stream>>>(s, a, wb + O_BS_W1T, bs_l1_b,
                                      wb + O_BS_W2T, bs_l2_b, X2BS);
    k_bs_gru<0><<<64, 256, 0, stream>>>(X2BS, wb + O_BS_WIH0, bs_bih0, bs_bhh0,
                                        H0BS, nullptr);
    k_bs_gru<1><<<64, 256, 0, stream>>>(H0BS, wb + O_BS_WIH1, bs_bih1, bs_bhh1,
                                        nullptr, HBS);
    k_final<<<64, 256, 0, stream>>>(SSUM, HBS, wb + O_GATWT, wb + O_EV1T,
                                    ev1_b, ev2_w, ev2_b, (float*)d_out);
}

// Round 4
// 359.341 us; speedup vs baseline: 1.7261x; 1.0314x over previous
//
#include <hip/hip_runtime.h>

// ---------------------------------------------------------------------------
// HetGAT critic on MI355X (gfx950), bf16-MFMA implementation.
//
// Algebraic simplification: softmax(axis=1) + einsum('bij,bjf->bf') makes the
// attention sum to exactly 1 per column => h_prime = (sum_nodes emb) @ gat_w.
// gat_a / adj / leaky_relu / softmax are dead code.
//
// Round-3 structure:
//  * k_ue_l1l2: 512thr/128rows; s,a staged once into LDS (bf16); wave w owns
//    n-tile w with weight frags loop-invariant in regs.
//  * k_scan: gi GEMM fused in; 8 waves x 16 cols; Wih/Whh frags in regs;
//    x prefetch DEPTH 2 (t-loop unrolled by 2, static reg buffers);
//    merged r/z accumulators (gi chained into gh acc); setprio around MFMA;
//    h double-buffered in LDS, one lgkm-only barrier per step.
//  * k_bs_final: entire BS branch (l1l2 -> gru0 -> gru1, h0=0 => gh==bhh)
//    plus the final GAT/ev head fused into one 64-block kernel with LDS
//    handoffs (no global round-trips, 3 fewer launches).
//
// MFMA v_mfma_f32_16x16x32_bf16 layouts:
//   A[m][k]: m=lane&15, k=(lane>>4)*8+i   (8 contiguous bf16 per lane)
//   B[k][n]: n=lane&15, k=(lane>>4)*8+i   (weights stored transposed [N][K])
//   D[m][n]: n=lane&15, m=(lane>>4)*4+reg
// ---------------------------------------------------------------------------

typedef unsigned short u16;
typedef __bf16  bf16x8  __attribute__((ext_vector_type(8)));
typedef short   short8  __attribute__((ext_vector_type(8)));
typedef u16     u16x4   __attribute__((ext_vector_type(4)));
typedef float   floatx4 __attribute__((ext_vector_type(4)));

#define DEVI __device__ __forceinline__
#define MFMA(a, b, c) __builtin_amdgcn_mfma_f32_16x16x32_bf16((a), (b), (c), 0, 0, 0)

DEVI u16 f2b(float f) {                       // f32 -> bf16 bits, RNE
    unsigned u = __float_as_uint(f);
    u += 0x7fffu + ((u >> 16) & 1u);
    return (u16)(u >> 16);
}
DEVI float b2f(u16 s) { return __uint_as_float(((unsigned)s) << 16); }
DEVI float sigm(float x) { return 1.f / (1.f + __expf(-x)); }
DEVI float tanh_(float x) { return 1.f - 2.f / (__expf(2.f * x) + 1.f); }

DEVI bf16x8 ldfrag(const u16* q) {            // 8 contiguous bf16 (16B aligned)
    return *reinterpret_cast<const bf16x8*>(q);
}
DEVI bf16x8 ldfrag_f32(const float* q) {      // 8 contiguous f32 -> bf16 frag
    float4 u = *reinterpret_cast<const float4*>(q);
    float4 v = *reinterpret_cast<const float4*>(q + 4);
    short8 pk;
    pk[0] = (short)f2b(u.x); pk[1] = (short)f2b(u.y);
    pk[2] = (short)f2b(u.z); pk[3] = (short)f2b(u.w);
    pk[4] = (short)f2b(v.x); pk[5] = (short)f2b(v.y);
    pk[6] = (short)f2b(v.z); pk[7] = (short)f2b(v.w);
    return __builtin_bit_cast(bf16x8, pk);
}

// bf16 weight offsets inside ws (elements)
enum : int {
    O_UE_W1T  = 0,        // [128][160]
    O_UE_W2T  = 20480,    // [128][128]
    O_UE_WIH0 = 36864,    // [384][128]
    O_UE_WHH0 = 86016,
    O_UE_WIH1 = 135168,
    O_UE_WHH1 = 184320,
    O_BS_W1T  = 233472,   // [128][320]
    O_BS_W2T  = 274432,
    O_BS_WIH0 = 290816,
    O_BS_WIH1 = 339968,
    O_GATWT   = 389120,   // [128][128]
    O_EV1T    = 405504,   // [128][128]
};
// ws byte offsets
#define WB_X2   1048576u
#define WB_Y0   34603008u
#define WB_SSUM 139460608u

// ---------------------------------------------------------------------------
__global__ __launch_bounds__(256) void k_prep(
    const float* __restrict__ ue1, const float* __restrict__ ue2,
    const float* __restrict__ uw0, const float* __restrict__ uh0,
    const float* __restrict__ uw1, const float* __restrict__ uh1,
    const float* __restrict__ bs1, const float* __restrict__ bs2,
    const float* __restrict__ bw0, const float* __restrict__ bw1,
    const float* __restrict__ gw,  const float* __restrict__ e1,
    u16* __restrict__ out)
{
    const int tid = blockIdx.x * blockDim.x + threadIdx.x;
    const int stride = gridDim.x * blockDim.x;
    auto cvt = [&](const float* s, int off, int n) {
        for (int i = tid; i < n; i += stride) out[off + i] = f2b(s[i]);
    };
    auto tcv = [&](const float* s, int off, int K, int N) {  // [K,N] -> [N,K]
        const int tot = K * N;
        for (int i = tid; i < tot; i += stride) {
            int nn = i / K, kk = i - nn * K;
            out[off + i] = f2b(s[kk * N + nn]);
        }
    };
    tcv(ue1, O_UE_W1T, 160, 128);  tcv(ue2, O_UE_W2T, 128, 128);
    cvt(uw0, O_UE_WIH0, 49152);    cvt(uh0, O_UE_WHH0, 49152);
    cvt(uw1, O_UE_WIH1, 49152);    cvt(uh1, O_UE_WHH1, 49152);
    tcv(bs1, O_BS_W1T, 320, 128);  tcv(bs2, O_BS_W2T, 128, 128);
    cvt(bw0, O_BS_WIH0, 49152);    cvt(bw1, O_BS_WIH1, 49152);
    tcv(gw,  O_GATWT, 128, 128);   tcv(e1,  O_EV1T, 128, 128);
}

// ---------------------------------------------------------------------------
// UE l1(relu) + l2(sigmoid), fused.  512 thr, 128 rows/block, grid 1024.
__global__ __launch_bounds__(512, 2) void k_ue_l1l2(
    const float* __restrict__ s, const float* __restrict__ a,
    const u16* __restrict__ W1T, const float* __restrict__ b1,
    const u16* __restrict__ W2T, const float* __restrict__ b2,
    u16* __restrict__ X2)
{
    __shared__ __align__(16) u16 A1[128][168];   // 160 cols + pad
    __shared__ __align__(16) u16 H[128][136];    // 128 cols + pad
    const int tid = threadIdx.x;
    const int w = tid >> 6, lane = tid & 63;
    const int lm = lane & 15, lg = lane >> 4;
    const int r0 = blockIdx.x * 128;

    bf16x8 bw1[5], bw2[4];
#pragma unroll
    for (int ks = 0; ks < 5; ++ks)
        bw1[ks] = ldfrag(W1T + (w * 16 + lm) * 160 + ks * 32 + lg * 8);
#pragma unroll
    for (int ks = 0; ks < 4; ++ks)
        bw2[ks] = ldfrag(W2T + (w * 16 + lm) * 128 + ks * 32 + lg * 8);
    const float bias1 = b1[w * 16 + lm];
    const float bias2 = b2[w * 16 + lm];

#pragma unroll
    for (int it = 0; it < 8; ++it) {
        const int fidx = it * 512 + tid;
        const int row = fidx >> 5, c4 = fidx & 31;
        const int r = r0 + row, bb = r >> 5, tt = r & 31;
        float4 v = *reinterpret_cast<const float4*>(s + (size_t)bb * 4352 + tt * 128 + c4 * 4);
        u16x4 p = {f2b(v.x), f2b(v.y), f2b(v.z), f2b(v.w)};
        *reinterpret_cast<u16x4*>(&A1[row][c4 * 4]) = p;
    }
#pragma unroll
    for (int it = 0; it < 2; ++it) {
        const int fidx = it * 512 + tid;
        const int row = fidx >> 3, c4 = fidx & 7;
        const int r = r0 + row, bb = r >> 5, tt = r & 31;
        float4 v = *reinterpret_cast<const float4*>(a + (size_t)bb * 1088 + tt * 32 + c4 * 4);
        u16x4 p = {f2b(v.x), f2b(v.y), f2b(v.z), f2b(v.w)};
        *reinterpret_cast<u16x4*>(&A1[row][128 + c4 * 4]) = p;
    }
    __syncthreads();

#pragma unroll
    for (int mt = 0; mt < 8; ++mt) {
        bf16x8 af[5];
#pragma unroll
        for (int ks = 0; ks < 5; ++ks)
            af[ks] = ldfrag(&A1[mt * 16 + lm][ks * 32 + lg * 8]);
        floatx4 acc = {0.f, 0.f, 0.f, 0.f};
#pragma unroll
        for (int ks = 0; ks < 5; ++ks) acc = MFMA(af[ks], bw1[ks], acc);
#pragma unroll
        for (int i = 0; i < 4; ++i) {
            float x = acc[i] + bias1;
            H[mt * 16 + lg * 4 + i][w * 16 + lm] = f2b(x > 0.f ? x : 0.f);
        }
    }
    __syncthreads();

#pragma unroll
    for (int mt = 0; mt < 8; ++mt) {
        bf16x8 af[4];
#pragma unroll
        for (int ks = 0; ks < 4; ++ks)
            af[ks] = ldfrag(&H[mt * 16 + lm][ks * 32 + lg * 8]);
        floatx4 acc = {0.f, 0.f, 0.f, 0.f};
#pragma unroll
        for (int ks = 0; ks < 4; ++ks) acc = MFMA(af[ks], bw2[ks], acc);
#pragma unroll
        for (int i = 0; i < 4; ++i)
            X2[(size_t)(r0 + mt * 16 + lg * 4 + i) * 128 + w * 16 + lm] =
                f2b(sigm(acc[i] + bias2));
    }
}

// ---------------------------------------------------------------------------
// Fused GRU layer: gi GEMM + time scan.  Block = 16 batch rows, 8 waves;
// wave w owns dh cols [w*16,w*16+16).  Depth-2 x prefetch (loop unroll x2,
// static reg buffers), merged r/z accumulators, setprio around MFMA.
#define SCAN_STEP(RBUF, WBUF, XA, TCUR, PREF_T)                               \
  {                                                                           \
    bf16x8 af[4];                                                             \
    _Pragma("unroll") for (int ks = 0; ks < 4; ++ks)                          \
        af[ks] = ldfrag(&RBUF[lm][ks * 32 + lg * 8]);                         \
    floatx4 accR{0.f,0.f,0.f,0.f}, accZ{0.f,0.f,0.f,0.f};                     \
    floatx4 accGN{0.f,0.f,0.f,0.f}, accHN{0.f,0.f,0.f,0.f};                   \
    __builtin_amdgcn_s_setprio(1);                                            \
    _Pragma("unroll") for (int ks = 0; ks < 4; ++ks) {                        \
        accR  = MFMA(XA[ks], bwi[0][ks], accR);                               \
        accZ  = MFMA(XA[ks], bwi[1][ks], accZ);                               \
        accGN = MFMA(XA[ks], bwi[2][ks], accGN);                              \
    }                                                                         \
    if ((PREF_T) < 32) {                                                      \
        _Pragma("unroll") for (int ks = 0; ks < 4; ++ks)                      \
            XA[ks] = ldfrag(xp + (PREF_T) * 128 + ks * 32);                   \
    }                                                                         \
    _Pragma("unroll") for (int ks = 0; ks < 4; ++ks) {                        \
        accR = MFMA(af[ks], bwh[0][ks], accR);                                \
        accZ = MFMA(af[ks], bwh[1][ks], accZ);                                \
        accHN = MFMA(af[ks], bwh[2][ks], accHN);                              \
    }                                                                         \
    __builtin_amdgcn_s_setprio(0);                                            \
    _Pragma("unroll") for (int i = 0; i < 4; ++i) {                           \
        const float rr = sigm(accR[i] + br);                                  \
        const float zz = sigm(accZ[i] + bz);                                  \
        const float nn = tanh_(accGN[i] + bni + rr * (accHN[i] + bnh));       \
        const float hn = (1.f - zz) * nn + zz * hreg[i];                      \
        hreg[i] = hn;                                                         \
        if (MODE == 1) ssum[i] += hn;                                         \
        const u16 hv = f2b(hn);                                               \
        WBUF[lg * 4 + i][c] = hv;                                             \
        if (MODE == 0)                                                        \
            Y[((size_t)(b0 + lg * 4 + i) * 32 + (TCUR)) * 128 + c] = hv;      \
    }                                                                         \
    __builtin_amdgcn_sched_barrier(0);                                        \
    asm volatile("s_waitcnt lgkmcnt(0)" ::: "memory");                        \
    __builtin_amdgcn_s_barrier();                                             \
    __builtin_amdgcn_sched_barrier(0);                                        \
  }

template <int MODE>
__global__ __launch_bounds__(512, 2) void k_scan(
    const u16* __restrict__ X, const u16* __restrict__ WIH,
    const u16* __restrict__ WHH,
    const float* __restrict__ bih, const float* __restrict__ bhh,
    u16* __restrict__ Y, float* __restrict__ Ssum)
{
    __shared__ __align__(16) u16 hb0[16][136];
    __shared__ __align__(16) u16 hb1[16][136];
    const int w = threadIdx.x >> 6, lane = threadIdx.x & 63;
    const int lm = lane & 15, lg = lane >> 4;
    const int b0 = blockIdx.x * 16;
    const int c = w * 16 + lm;

    bf16x8 bwh[3][4], bwi[3][4];
#pragma unroll
    for (int g = 0; g < 3; ++g)
#pragma unroll
        for (int ks = 0; ks < 4; ++ks) {
            bwh[g][ks] = ldfrag(WHH + (g * 128 + c) * 128 + ks * 32 + lg * 8);
            bwi[g][ks] = ldfrag(WIH + (g * 128 + c) * 128 + ks * 32 + lg * 8);
        }

    for (int i = threadIdx.x; i < 16 * 136; i += 512) {
        ((u16*)hb0)[i] = 0; ((u16*)hb1)[i] = 0;
    }

    const float br  = bih[c] + bhh[c];
    const float bz  = bih[128 + c] + bhh[128 + c];
    const float bni = bih[256 + c], bnh = bhh[256 + c];

    const u16* xp = X + (size_t)(b0 + lm) * 32 * 128 + lg * 8;
    bf16x8 xa[4], xb[4];
#pragma unroll
    for (int ks = 0; ks < 4; ++ks) {
        xa[ks] = ldfrag(xp + ks * 32);            // t=0
        xb[ks] = ldfrag(xp + 128 + ks * 32);      // t=1
    }

    float hreg[4] = {}, ssum[4] = {};
    __syncthreads();

    for (int tt = 0; tt < 32; tt += 2) {
        SCAN_STEP(hb0, hb1, xa, tt,     tt + 2);
        SCAN_STEP(hb1, hb0, xb, tt + 1, tt + 3);
    }
    if (MODE == 1) {
#pragma unroll
        for (int i = 0; i < 4; ++i)
            Ssum[(size_t)(b0 + lg * 4 + i) * 128 + c] = ssum[i];
    }
}

// ---------------------------------------------------------------------------
// Entire BS branch + final head, one 64-block kernel with LDS handoffs:
//  ph1: l1(relu,K=320)+l2(sigmoid) -> X2L (LDS bf16)
//  ph2: gru0 (h0=0 => gh==bhh) X2L -> H0L (LDS bf16)
//  ph3: gru1 H0L -> HL (LDS f32)
//  ph4: S=SSUM+HL; out = relu(elu(S@gat_w)@ev1+b1)@ev2+b2
__global__ __launch_bounds__(256, 2) void k_bs_final(
    const float* __restrict__ s, const float* __restrict__ a,
    const u16* __restrict__ W1T, const float* __restrict__ b1,
    const u16* __restrict__ W2T, const float* __restrict__ b2,
    const u16* __restrict__ WIH0, const float* __restrict__ bih0,
    const float* __restrict__ bhh0,
    const u16* __restrict__ WIH1, const float* __restrict__ bih1,
    const float* __restrict__ bhh1,
    const float* __restrict__ Ssum,
    const u16* __restrict__ GATWT, const u16* __restrict__ EV1T,
    const float* __restrict__ ev1b, const float* __restrict__ ev2w,
    const float* __restrict__ ev2b, float* __restrict__ out)
{
    __shared__ __align__(16) char smem[52224];
    u16   (*X2L)[136] = reinterpret_cast<u16(*)[136]>(smem);          // 17408
    u16   (*HBP)[136] = reinterpret_cast<u16(*)[136]>(smem + 17408);  // 17408
    u16   (*H0L)[136] = reinterpret_cast<u16(*)[136]>(smem + 34816);  // 17408
    float (*HL)[132]  = reinterpret_cast<float(*)[132]>(smem);        // 33792 (over X2L+HBP)
    u16   (*HBF)[136] = reinterpret_cast<u16(*)[136]>(smem + 34816);  // over H0L
    float (*XBF)[132] = reinterpret_cast<float(*)[132]>(smem);        // over HL

    const int w = threadIdx.x >> 6, lane = threadIdx.x & 63;
    const int lm = lane & 15, lg = lane >> 4;
    const int r0 = blockIdx.x * 64 + w * 16;
    const int lr = w * 16;                        // local row base

    // ---- phase 1: l1 + l2 ----
    {
        const float* srow = s + (size_t)(r0 + lm) * 4352 + 4096 + lg * 8;
        const float* arow = a + (size_t)(r0 + lm) * 1088 + 1024 + lg * 8;
        bf16x8 af[10];
#pragma unroll
        for (int ks = 0; ks < 8; ++ks) af[ks] = ldfrag_f32(srow + ks * 32);
        af[8] = ldfrag_f32(arow);
        af[9] = ldfrag_f32(arow + 32);

        const u16* wb1 = W1T + lm * 320 + lg * 8;
#pragma unroll
        for (int n = 0; n < 8; ++n) {
            floatx4 acc = {0.f, 0.f, 0.f, 0.f};
#pragma unroll
            for (int ks = 0; ks < 10; ++ks)
                acc = MFMA(af[ks], ldfrag(wb1 + n * 5120 + ks * 32), acc);
            const float bias = b1[n * 16 + lm];
#pragma unroll
            for (int i = 0; i < 4; ++i) {
                float x = acc[i] + bias;
                HBP[lr + lg * 4 + i][n * 16 + lm] = f2b(x > 0.f ? x : 0.f);
            }
        }
        __syncthreads();

        bf16x8 af2[4];
#pragma unroll
        for (int ks = 0; ks < 4; ++ks)
            af2[ks] = ldfrag(&HBP[lr + lm][ks * 32 + lg * 8]);
        const u16* wb2 = W2T + lm * 128 + lg * 8;
#pragma unroll
        for (int n = 0; n < 8; ++n) {
            floatx4 acc = {0.f, 0.f, 0.f, 0.f};
#pragma unroll
            for (int ks = 0; ks < 4; ++ks)
                acc = MFMA(af2[ks], ldfrag(wb2 + n * 2048 + ks * 32), acc);
            const float bias = b2[n * 16 + lm];
#pragma unroll
            for (int i = 0; i < 4; ++i)
                X2L[lr + lg * 4 + i][n * 16 + lm] = f2b(sigm(acc[i] + bias));
        }
    }
    __syncthreads();

    // ---- phase 2: gru0 (X2L -> H0L) ----
    {
        bf16x8 ax[4];
#pragma unroll
        for (int ks = 0; ks < 4; ++ks)
            ax[ks] = ldfrag(&X2L[lr + lm][ks * 32 + lg * 8]);
        floatx4 acc[24];
#pragma unroll
        for (int j = 0; j < 24; ++j) acc[j] = floatx4{0.f, 0.f, 0.f, 0.f};
        const u16* wbp = WIH0 + lm * 128 + lg * 8;
#pragma unroll
        for (int j = 0; j < 24; ++j)
#pragma unroll
            for (int ks = 0; ks < 4; ++ks)
                acc[j] = MFMA(ax[ks], ldfrag(wbp + j * 2048 + ks * 32), acc[j]);
#pragma unroll
        for (int ct = 0; ct < 8; ++ct) {
            const int cc = ct * 16 + lm;
            const float brr = bih0[cc] + bhh0[cc];
            const float bzz = bih0[128 + cc] + bhh0[128 + cc];
            const float bni = bih0[256 + cc], bnh = bhh0[256 + cc];
#pragma unroll
            for (int i = 0; i < 4; ++i) {
                const float rr = sigm(acc[ct][i] + brr);
                const float zz = sigm(acc[8 + ct][i] + bzz);
                const float nn = tanh_(acc[16 + ct][i] + bni + rr * bnh);
                H0L[lr + lg * 4 + i][cc] = f2b((1.f - zz) * nn);
            }
        }
    }
    __syncthreads();

    // ---- phase 3: gru1 (H0L -> HL f32) ----
    {
        bf16x8 ax[4];
#pragma unroll
        for (int ks = 0; ks < 4; ++ks)
            ax[ks] = ldfrag(&H0L[lr + lm][ks * 32 + lg * 8]);
        floatx4 acc[24];
#pragma unroll
        for (int j = 0; j < 24; ++j) acc[j] = floatx4{0.f, 0.f, 0.f, 0.f};
        const u16* wbp = WIH1 + lm * 128 + lg * 8;
#pragma unroll
        for (int j = 0; j < 24; ++j)
#pragma unroll
            for (int ks = 0; ks < 4; ++ks)
                acc[j] = MFMA(ax[ks], ldfrag(wbp + j * 2048 + ks * 32), acc[j]);
        __syncthreads();   // H0L reads done before HL overlay writes? (disjoint regions; barrier for ph1/2 region reuse safety)
#pragma unroll
        for (int ct = 0; ct < 8; ++ct) {
            const int cc = ct * 16 + lm;
            const float brr = bih1[cc] + bhh1[cc];
            const float bzz = bih1[128 + cc] + bhh1[128 + cc];
            const float bni = bih1[256 + cc], bnh = bhh1[256 + cc];
#pragma unroll
            for (int i = 0; i < 4; ++i) {
                const float rr = sigm(acc[ct][i] + brr);
                const float zz = sigm(acc[8 + ct][i] + bzz);
                const float nn = tanh_(acc[16 + ct][i] + bni + rr * bnh);
                HL[lr + lg * 4 + i][cc] = (1.f - zz) * nn;
            }
        }
    }
    __syncthreads();

    // ---- phase 4: final head ----
    {
        const float* p1 = Ssum + (size_t)(r0 + lm) * 128 + lg * 8;
        bf16x8 af[4];
#pragma unroll
        for (int ks = 0; ks < 4; ++ks) {
            float4 u  = *reinterpret_cast<const float4*>(p1 + ks * 32);
            float4 u2 = *reinterpret_cast<const float4*>(p1 + ks * 32 + 4);
            float4 v  = *reinterpret_cast<const float4*>(&HL[lr + lm][ks * 32 + lg * 8]);
            float4 v2 = *reinterpret_cast<const float4*>(&HL[lr + lm][ks * 32 + lg * 8 + 4]);
            short8 pk;
            pk[0] = (short)f2b(u.x + v.x);  pk[1] = (short)f2b(u.y + v.y);
            pk[2] = (short)f2b(u.z + v.z);  pk[3] = (short)f2b(u.w + v.w);
            pk[4] = (short)f2b(u2.x + v2.x); pk[5] = (short)f2b(u2.y + v2.y);
            pk[6] = (short)f2b(u2.z + v2.z); pk[7] = (short)f2b(u2.w + v2.w);
            af[ks] = __builtin_bit_cast(bf16x8, pk);
        }
        __syncthreads();   // all HL reads complete before XBF overlay writes
        const u16* gwp = GATWT + lm * 128 + lg * 8;
#pragma unroll
        for (int n = 0; n < 8; ++n) {
            floatx4 acc = {0.f, 0.f, 0.f, 0.f};
#pragma unroll
            for (int ks = 0; ks < 4; ++ks)
                acc = MFMA(af[ks], ldfrag(gwp + n * 2048 + ks * 32), acc);
#pragma unroll
            for (int i = 0; i < 4; ++i) {
                float x = acc[i];
                x = x > 0.f ? x : (__expf(x) - 1.f);            // elu
                HBF[lr + lg * 4 + i][n * 16 + lm] = f2b(x);
            }
        }
        __syncthreads();

        bf16x8 af2[4];
#pragma unroll
        for (int ks = 0; ks < 4; ++ks)
            af2[ks] = ldfrag(&HBF[lr + lm][ks * 32 + lg * 8]);
        const u16* e1p = EV1T + lm * 128 + lg * 8;
#pragma unroll
        for (int n = 0; n < 8; ++n) {
            floatx4 acc = {0.f, 0.f, 0.f, 0.f};
#pragma unroll
            for (int ks = 0; ks < 4; ++ks)
                acc = MFMA(af2[ks], ldfrag(e1p + n * 2048 + ks * 32), acc);
            const float bias = ev1b[n * 16 + lm];
#pragma unroll
            for (int i = 0; i < 4; ++i) {
                float v = acc[i] + bias;
                XBF[lr + lg * 4 + i][n * 16 + lm] = v > 0.f ? v : 0.f;  // relu
            }
        }
        __syncthreads();

        float sacc = 0.f;
#pragma unroll
        for (int k = 0; k < 32; ++k) {
            const int cc = lg * 32 + k;
            sacc += XBF[lr + lm][cc] * ev2w[cc];
        }
        sacc += __shfl_xor(sacc, 16, 64);
        sacc += __shfl_xor(sacc, 32, 64);
        if (lg == 0) out[r0 + lm] = sacc + ev2b[0];
    }
}

// ---------------------------------------------------------------------------
extern "C" void kernel_launch(void* const* d_in, const int* in_sizes, int n_in,
                              void* d_out, int out_size, void* d_ws, size_t ws_size,
                              hipStream_t stream)
{
    (void)in_sizes; (void)n_in; (void)out_size; (void)ws_size;
    const float* s       = (const float*)d_in[0];
    const float* a       = (const float*)d_in[1];
    const float* ue_l1_w = (const float*)d_in[2];
    const float* ue_l1_b = (const float*)d_in[3];
    const float* ue_l2_w = (const float*)d_in[4];
    const float* ue_l2_b = (const float*)d_in[5];
    const float* ue_wih0 = (const float*)d_in[6];
    const float* ue_whh0 = (const float*)d_in[7];
    const float* ue_bih0 = (const float*)d_in[8];
    const float* ue_bhh0 = (const float*)d_in[9];
    const float* ue_wih1 = (const float*)d_in[10];
    const float* ue_whh1 = (const float*)d_in[11];
    const float* ue_bih1 = (const float*)d_in[12];
    const float* ue_bhh1 = (const float*)d_in[13];
    const float* bs_l1_w = (const float*)d_in[14];
    const float* bs_l1_b = (const float*)d_in[15];
    const float* bs_l2_w = (const float*)d_in[16];
    const float* bs_l2_b = (const float*)d_in[17];
    const float* bs_wih0 = (const float*)d_in[18];
    const float* bs_bih0 = (const float*)d_in[20];
    const float* bs_bhh0 = (const float*)d_in[21];
    const float* bs_wih1 = (const float*)d_in[22];
    const float* bs_bih1 = (const float*)d_in[24];
    const float* bs_bhh1 = (const float*)d_in[25];
    const float* gat_w   = (const float*)d_in[26];
    const float* ev1_w   = (const float*)d_in[29];
    const float* ev1_b   = (const float*)d_in[30];
    const float* ev2_w   = (const float*)d_in[31];
    const float* ev2_b   = (const float*)d_in[32];

    char* ws = (char*)d_ws;
    u16*   wb   = (u16*)ws;
    u16*   X2   = (u16*)(ws + WB_X2);
    u16*   Y0   = (u16*)(ws + WB_Y0);
    float* SSUM = (float*)(ws + WB_SSUM);

    k_prep<<<256, 256, 0, stream>>>(ue_l1_w, ue_l2_w, ue_wih0, ue_whh0,
                                    ue_wih1, ue_whh1, bs_l1_w, bs_l2_w,
                                    bs_wih0, bs_wih1, gat_w, ev1_w, wb);
    k_ue_l1l2<<<1024, 512, 0, stream>>>(s, a, wb + O_UE_W1T, ue_l1_b,
                                        wb + O_UE_W2T, ue_l2_b, X2);
    k_scan<0><<<256, 512, 0, stream>>>(X2, wb + O_UE_WIH0, wb + O_UE_WHH0,
                                       ue_bih0, ue_bhh0, Y0, nullptr);
    k_scan<1><<<256, 512, 0, stream>>>(Y0, wb + O_UE_WIH1, wb + O_UE_WHH1,
                                       ue_bih1, ue_bhh1, nullptr, SSUM);
    k_bs_final<<<64, 256, 0, stream>>>(s, a, wb + O_BS_W1T, bs_l1_b,
                                       wb + O_BS_W2T, bs_l2_b,
                                       wb + O_BS_WIH0, bs_bih0, bs_bhh0,
                                       wb + O_BS_WIH1, bs_bih1, bs_bhh1,
                                       SSUM, wb + O_GATWT, wb + O_EV1T,
                                       ev1_b, ev2_w, ev2_b, (float*)d_out);
}

// Round 6
// 306.887 us; speedup vs baseline: 2.0212x; 1.1709x over previous
//
#include <hip/hip_runtime.h>

// ---------------------------------------------------------------------------
// HetGAT critic on MI355X (gfx950), bf16-MFMA implementation.
//
// Algebraic simplification: softmax(axis=1) + einsum('bij,bjf->bf') makes the
// attention sum to exactly 1 per column => h_prime = (sum_nodes emb) @ gat_w.
// gat_a / adj / leaky_relu / softmax are dead code.
//
// Round-5: identical to round-4 source (bench infra failed; resubmit).
//  * k_ue_l1l2: 512thr/128rows; s,a staged once into LDS (bf16); wave w owns
//    n-tile w with weight frags loop-invariant in regs.
//  * k_scan: gi GEMM fused in; 8 waves x 16 cols; Wih/Whh frags in regs;
//    x prefetch depth 2; merged r/z accumulators; setprio around MFMA;
//    h double-buffered in LDS, one lgkm-only barrier per step.
//  * k_bs_final: BS branch + final head: 256 blocks x 512 thr, 16 rows/block,
//    wave w owns cols [16w,16w+16) in every phase; per-phase weight frags are
//    small batched loads; intermediates in LDS.
//
// MFMA v_mfma_f32_16x16x32_bf16 layouts:
//   A[m][k]: m=lane&15, k=(lane>>4)*8+i   (8 contiguous bf16 per lane)
//   B[k][n]: n=lane&15, k=(lane>>4)*8+i   (weights stored transposed [N][K])
//   D[m][n]: n=lane&15, m=(lane>>4)*4+reg
// ---------------------------------------------------------------------------

typedef unsigned short u16;
typedef __bf16  bf16x8  __attribute__((ext_vector_type(8)));
typedef short   short8  __attribute__((ext_vector_type(8)));
typedef u16     u16x4   __attribute__((ext_vector_type(4)));
typedef float   floatx4 __attribute__((ext_vector_type(4)));

#define DEVI __device__ __forceinline__
#define MFMA(a, b, c) __builtin_amdgcn_mfma_f32_16x16x32_bf16((a), (b), (c), 0, 0, 0)

DEVI u16 f2b(float f) {                       // f32 -> bf16 bits, RNE
    unsigned u = __float_as_uint(f);
    u += 0x7fffu + ((u >> 16) & 1u);
    return (u16)(u >> 16);
}
DEVI float b2f(u16 s) { return __uint_as_float(((unsigned)s) << 16); }
DEVI float sigm(float x) { return 1.f / (1.f + __expf(-x)); }
DEVI float tanh_(float x) { return 1.f - 2.f / (__expf(2.f * x) + 1.f); }

DEVI bf16x8 ldfrag(const u16* q) {            // 8 contiguous bf16 (16B aligned)
    return *reinterpret_cast<const bf16x8*>(q);
}
DEVI bf16x8 ldfrag_f32(const float* q) {      // 8 contiguous f32 -> bf16 frag
    float4 u = *reinterpret_cast<const float4*>(q);
    float4 v = *reinterpret_cast<const float4*>(q + 4);
    short8 pk;
    pk[0] = (short)f2b(u.x); pk[1] = (short)f2b(u.y);
    pk[2] = (short)f2b(u.z); pk[3] = (short)f2b(u.w);
    pk[4] = (short)f2b(v.x); pk[5] = (short)f2b(v.y);
    pk[6] = (short)f2b(v.z); pk[7] = (short)f2b(v.w);
    return __builtin_bit_cast(bf16x8, pk);
}

// bf16 weight offsets inside ws (elements)
enum : int {
    O_UE_W1T  = 0,        // [128][160]
    O_UE_W2T  = 20480,    // [128][128]
    O_UE_WIH0 = 36864,    // [384][128]
    O_UE_WHH0 = 86016,
    O_UE_WIH1 = 135168,
    O_UE_WHH1 = 184320,
    O_BS_W1T  = 233472,   // [128][320]
    O_BS_W2T  = 274432,
    O_BS_WIH0 = 290816,
    O_BS_WIH1 = 339968,
    O_GATWT   = 389120,   // [128][128]
    O_EV1T    = 405504,   // [128][128]
};
// ws byte offsets
#define WB_X2   1048576u
#define WB_Y0   34603008u
#define WB_SSUM 139460608u

// ---------------------------------------------------------------------------
__global__ __launch_bounds__(256) void k_prep(
    const float* __restrict__ ue1, const float* __restrict__ ue2,
    const float* __restrict__ uw0, const float* __restrict__ uh0,
    const float* __restrict__ uw1, const float* __restrict__ uh1,
    const float* __restrict__ bs1, const float* __restrict__ bs2,
    const float* __restrict__ bw0, const float* __restrict__ bw1,
    const float* __restrict__ gw,  const float* __restrict__ e1,
    u16* __restrict__ out)
{
    const int tid = blockIdx.x * blockDim.x + threadIdx.x;
    const int stride = gridDim.x * blockDim.x;
    auto cvt = [&](const float* s, int off, int n) {
        for (int i = tid; i < n; i += stride) out[off + i] = f2b(s[i]);
    };
    auto tcv = [&](const float* s, int off, int K, int N) {  // [K,N] -> [N,K]
        const int tot = K * N;
        for (int i = tid; i < tot; i += stride) {
            int nn = i / K, kk = i - nn * K;
            out[off + i] = f2b(s[kk * N + nn]);
        }
    };
    tcv(ue1, O_UE_W1T, 160, 128);  tcv(ue2, O_UE_W2T, 128, 128);
    cvt(uw0, O_UE_WIH0, 49152);    cvt(uh0, O_UE_WHH0, 49152);
    cvt(uw1, O_UE_WIH1, 49152);    cvt(uh1, O_UE_WHH1, 49152);
    tcv(bs1, O_BS_W1T, 320, 128);  tcv(bs2, O_BS_W2T, 128, 128);
    cvt(bw0, O_BS_WIH0, 49152);    cvt(bw1, O_BS_WIH1, 49152);
    tcv(gw,  O_GATWT, 128, 128);   tcv(e1,  O_EV1T, 128, 128);
}

// ---------------------------------------------------------------------------
// UE l1(relu) + l2(sigmoid), fused.  512 thr, 128 rows/block, grid 1024.
__global__ __launch_bounds__(512, 2) void k_ue_l1l2(
    const float* __restrict__ s, const float* __restrict__ a,
    const u16* __restrict__ W1T, const float* __restrict__ b1,
    const u16* __restrict__ W2T, const float* __restrict__ b2,
    u16* __restrict__ X2)
{
    __shared__ __align__(16) u16 A1[128][168];   // 160 cols + pad
    __shared__ __align__(16) u16 H[128][136];    // 128 cols + pad
    const int tid = threadIdx.x;
    const int w = tid >> 6, lane = tid & 63;
    const int lm = lane & 15, lg = lane >> 4;
    const int r0 = blockIdx.x * 128;

    bf16x8 bw1[5], bw2[4];
#pragma unroll
    for (int ks = 0; ks < 5; ++ks)
        bw1[ks] = ldfrag(W1T + (w * 16 + lm) * 160 + ks * 32 + lg * 8);
#pragma unroll
    for (int ks = 0; ks < 4; ++ks)
        bw2[ks] = ldfrag(W2T + (w * 16 + lm) * 128 + ks * 32 + lg * 8);
    const float bias1 = b1[w * 16 + lm];
    const float bias2 = b2[w * 16 + lm];

#pragma unroll
    for (int it = 0; it < 8; ++it) {
        const int fidx = it * 512 + tid;
        const int row = fidx >> 5, c4 = fidx & 31;
        const int r = r0 + row, bb = r >> 5, tt = r & 31;
        float4 v = *reinterpret_cast<const float4*>(s + (size_t)bb * 4352 + tt * 128 + c4 * 4);
        u16x4 p = {f2b(v.x), f2b(v.y), f2b(v.z), f2b(v.w)};
        *reinterpret_cast<u16x4*>(&A1[row][c4 * 4]) = p;
    }
#pragma unroll
    for (int it = 0; it < 2; ++it) {
        const int fidx = it * 512 + tid;
        const int row = fidx >> 3, c4 = fidx & 7;
        const int r = r0 + row, bb = r >> 5, tt = r & 31;
        float4 v = *reinterpret_cast<const float4*>(a + (size_t)bb * 1088 + tt * 32 + c4 * 4);
        u16x4 p = {f2b(v.x), f2b(v.y), f2b(v.z), f2b(v.w)};
        *reinterpret_cast<u16x4*>(&A1[row][128 + c4 * 4]) = p;
    }
    __syncthreads();

#pragma unroll
    for (int mt = 0; mt < 8; ++mt) {
        bf16x8 af[5];
#pragma unroll
        for (int ks = 0; ks < 5; ++ks)
            af[ks] = ldfrag(&A1[mt * 16 + lm][ks * 32 + lg * 8]);
        floatx4 acc = {0.f, 0.f, 0.f, 0.f};
#pragma unroll
        for (int ks = 0; ks < 5; ++ks) acc = MFMA(af[ks], bw1[ks], acc);
#pragma unroll
        for (int i = 0; i < 4; ++i) {
            float x = acc[i] + bias1;
            H[mt * 16 + lg * 4 + i][w * 16 + lm] = f2b(x > 0.f ? x : 0.f);
        }
    }
    __syncthreads();

#pragma unroll
    for (int mt = 0; mt < 8; ++mt) {
        bf16x8 af[4];
#pragma unroll
        for (int ks = 0; ks < 4; ++ks)
            af[ks] = ldfrag(&H[mt * 16 + lm][ks * 32 + lg * 8]);
        floatx4 acc = {0.f, 0.f, 0.f, 0.f};
#pragma unroll
        for (int ks = 0; ks < 4; ++ks) acc = MFMA(af[ks], bw2[ks], acc);
#pragma unroll
        for (int i = 0; i < 4; ++i)
            X2[(size_t)(r0 + mt * 16 + lg * 4 + i) * 128 + w * 16 + lm] =
                f2b(sigm(acc[i] + bias2));
    }
}

// ---------------------------------------------------------------------------
// Fused GRU layer: gi GEMM + time scan.  Block = 16 batch rows, 8 waves;
// wave w owns dh cols [w*16,w*16+16).  Depth-2 x prefetch, merged r/z
// accumulators, setprio around MFMA, one lgkm-only barrier per step.
#define SCAN_STEP(RBUF, WBUF, XA, TCUR, PREF_T)                               \
  {                                                                           \
    bf16x8 af[4];                                                             \
    _Pragma("unroll") for (int ks = 0; ks < 4; ++ks)                          \
        af[ks] = ldfrag(&RBUF[lm][ks * 32 + lg * 8]);                         \
    floatx4 accR{0.f,0.f,0.f,0.f}, accZ{0.f,0.f,0.f,0.f};                     \
    floatx4 accGN{0.f,0.f,0.f,0.f}, accHN{0.f,0.f,0.f,0.f};                   \
    __builtin_amdgcn_s_setprio(1);                                            \
    _Pragma("unroll") for (int ks = 0; ks < 4; ++ks) {                        \
        accR  = MFMA(XA[ks], bwi[0][ks], accR);                               \
        accZ  = MFMA(XA[ks], bwi[1][ks], accZ);                               \
        accGN = MFMA(XA[ks], bwi[2][ks], accGN);                              \
    }                                                                         \
    if ((PREF_T) < 32) {                                                      \
        _Pragma("unroll") for (int ks = 0; ks < 4; ++ks)                      \
            XA[ks] = ldfrag(xp + (PREF_T) * 128 + ks * 32);                   \
    }                                                                         \
    _Pragma("unroll") for (int ks = 0; ks < 4; ++ks) {                        \
        accR = MFMA(af[ks], bwh[0][ks], accR);                                \
        accZ = MFMA(af[ks], bwh[1][ks], accZ);                                \
        accHN = MFMA(af[ks], bwh[2][ks], accHN);                              \
    }                                                                         \
    __builtin_amdgcn_s_setprio(0);                                            \
    _Pragma("unroll") for (int i = 0; i < 4; ++i) {                           \
        const float rr = sigm(accR[i] + br);                                  \
        const float zz = sigm(accZ[i] + bz);                                  \
        const float nn = tanh_(accGN[i] + bni + rr * (accHN[i] + bnh));       \
        const float hn = (1.f - zz) * nn + zz * hreg[i];                      \
        hreg[i] = hn;                                                         \
        if (MODE == 1) ssum[i] += hn;                                         \
        const u16 hv = f2b(hn);                                               \
        WBUF[lg * 4 + i][c] = hv;                                             \
        if (MODE == 0)                                                        \
            Y[((size_t)(b0 + lg * 4 + i) * 32 + (TCUR)) * 128 + c] = hv;      \
    }                                                                         \
    __builtin_amdgcn_sched_barrier(0);                                        \
    asm volatile("s_waitcnt lgkmcnt(0)" ::: "memory");                        \
    __builtin_amdgcn_s_barrier();                                             \
    __builtin_amdgcn_sched_barrier(0);                                        \
  }

template <int MODE>
__global__ __launch_bounds__(512, 2) void k_scan(
    const u16* __restrict__ X, const u16* __restrict__ WIH,
    const u16* __restrict__ WHH,
    const float* __restrict__ bih, const float* __restrict__ bhh,
    u16* __restrict__ Y, float* __restrict__ Ssum)
{
    __shared__ __align__(16) u16 hb0[16][136];
    __shared__ __align__(16) u16 hb1[16][136];
    const int w = threadIdx.x >> 6, lane = threadIdx.x & 63;
    const int lm = lane & 15, lg = lane >> 4;
    const int b0 = blockIdx.x * 16;
    const int c = w * 16 + lm;

    bf16x8 bwh[3][4], bwi[3][4];
#pragma unroll
    for (int g = 0; g < 3; ++g)
#pragma unroll
        for (int ks = 0; ks < 4; ++ks) {
            bwh[g][ks] = ldfrag(WHH + (g * 128 + c) * 128 + ks * 32 + lg * 8);
            bwi[g][ks] = ldfrag(WIH + (g * 128 + c) * 128 + ks * 32 + lg * 8);
        }

    for (int i = threadIdx.x; i < 16 * 136; i += 512) {
        ((u16*)hb0)[i] = 0; ((u16*)hb1)[i] = 0;
    }

    const float br  = bih[c] + bhh[c];
    const float bz  = bih[128 + c] + bhh[128 + c];
    const float bni = bih[256 + c], bnh = bhh[256 + c];

    const u16* xp = X + (size_t)(b0 + lm) * 32 * 128 + lg * 8;
    bf16x8 xa[4], xb[4];
#pragma unroll
    for (int ks = 0; ks < 4; ++ks) {
        xa[ks] = ldfrag(xp + ks * 32);            // t=0
        xb[ks] = ldfrag(xp + 128 + ks * 32);      // t=1
    }

    float hreg[4] = {}, ssum[4] = {};
    __syncthreads();

    for (int tt = 0; tt < 32; tt += 2) {
        SCAN_STEP(hb0, hb1, xa, tt,     tt + 2);
        SCAN_STEP(hb1, hb0, xb, tt + 1, tt + 3);
    }
    if (MODE == 1) {
#pragma unroll
        for (int i = 0; i < 4; ++i)
            Ssum[(size_t)(b0 + lg * 4 + i) * 128 + c] = ssum[i];
    }
}

// ---------------------------------------------------------------------------
// BS branch + final head.  256 blocks x 512 thr; 16 rows/block; wave w owns
// cols [16w,16w+16) in every phase.  LDS handoffs; h0=0 => gh == bhh.
//  ph1a l1(relu,K=320) -> HBl   ph1b l2(sigmoid) -> X2b
//  ph2  gru0 -> H0b             ph3  gru1 -> HLf (f32)
//  ph4a S=Ssum+HLf; elu(S@gat_w) -> HBe   ph4b relu(.@ev1+b1) -> XBf
//  ph4c out = XBf@ev2 + b2
__global__ __launch_bounds__(512, 1) void k_bs_final(
    const float* __restrict__ s, const float* __restrict__ a,
    const u16* __restrict__ W1T, const float* __restrict__ b1,
    const u16* __restrict__ W2T, const float* __restrict__ b2,
    const u16* __restrict__ WIH0, const float* __restrict__ bih0,
    const float* __restrict__ bhh0,
    const u16* __restrict__ WIH1, const float* __restrict__ bih1,
    const float* __restrict__ bhh1,
    const float* __restrict__ Ssum,
    const u16* __restrict__ GATWT, const u16* __restrict__ EV1T,
    const float* __restrict__ ev1b, const float* __restrict__ ev2w,
    const float* __restrict__ ev2b, float* __restrict__ out)
{
    __shared__ __align__(16) u16 HBl[16][136];
    __shared__ __align__(16) u16 X2b[16][136];
    __shared__ __align__(16) u16 H0b[16][136];
    __shared__ __align__(16) float HLf[16][132];
    __shared__ __align__(16) u16 HBe[16][136];
    __shared__ __align__(16) float XBf[16][132];

    const int w = threadIdx.x >> 6, lane = threadIdx.x & 63;
    const int lm = lane & 15, lg = lane >> 4;
    const int r0 = blockIdx.x * 16;
    const int c = w * 16 + lm;                    // this wave's output column

    // ---- phase 1a: l1 (K=320) ----
    {
        const float* srow = s + (size_t)(r0 + lm) * 4352 + 4096 + lg * 8;
        const float* arow = a + (size_t)(r0 + lm) * 1088 + 1024 + lg * 8;
        bf16x8 af[10];
#pragma unroll
        for (int ks = 0; ks < 8; ++ks) af[ks] = ldfrag_f32(srow + ks * 32);
        af[8] = ldfrag_f32(arow);
        af[9] = ldfrag_f32(arow + 32);

        bf16x8 bw[10];
#pragma unroll
        for (int ks = 0; ks < 10; ++ks)
            bw[ks] = ldfrag(W1T + c * 320 + ks * 32 + lg * 8);
        floatx4 acc = {0.f, 0.f, 0.f, 0.f};
#pragma unroll
        for (int ks = 0; ks < 10; ++ks) acc = MFMA(af[ks], bw[ks], acc);
        const float bias = b1[c];
#pragma unroll
        for (int i = 0; i < 4; ++i) {
            float x = acc[i] + bias;
            HBl[lg * 4 + i][c] = f2b(x > 0.f ? x : 0.f);
        }
    }
    __syncthreads();

    // ---- phase 1b: l2 ----
    {
        bf16x8 af[4], bw[4];
#pragma unroll
        for (int ks = 0; ks < 4; ++ks) {
            af[ks] = ldfrag(&HBl[lm][ks * 32 + lg * 8]);
            bw[ks] = ldfrag(W2T + c * 128 + ks * 32 + lg * 8);
        }
        floatx4 acc = {0.f, 0.f, 0.f, 0.f};
#pragma unroll
        for (int ks = 0; ks < 4; ++ks) acc = MFMA(af[ks], bw[ks], acc);
        const float bias = b2[c];
#pragma unroll
        for (int i = 0; i < 4; ++i)
            X2b[lg * 4 + i][c] = f2b(sigm(acc[i] + bias));
    }
    __syncthreads();

    // ---- phase 2: gru0 (h0=0) ----
    {
        bf16x8 af[4], bw[3][4];
#pragma unroll
        for (int ks = 0; ks < 4; ++ks) {
            af[ks] = ldfrag(&X2b[lm][ks * 32 + lg * 8]);
#pragma unroll
            for (int g = 0; g < 3; ++g)
                bw[g][ks] = ldfrag(WIH0 + (g * 128 + c) * 128 + ks * 32 + lg * 8);
        }
        floatx4 aR{0,0,0,0}, aZ{0,0,0,0}, aN{0,0,0,0};
#pragma unroll
        for (int ks = 0; ks < 4; ++ks) {
            aR = MFMA(af[ks], bw[0][ks], aR);
            aZ = MFMA(af[ks], bw[1][ks], aZ);
            aN = MFMA(af[ks], bw[2][ks], aN);
        }
        const float brr = bih0[c] + bhh0[c];
        const float bzz = bih0[128 + c] + bhh0[128 + c];
        const float bni = bih0[256 + c], bnh = bhh0[256 + c];
#pragma unroll
        for (int i = 0; i < 4; ++i) {
            const float rr = sigm(aR[i] + brr);
            const float zz = sigm(aZ[i] + bzz);
            const float nn = tanh_(aN[i] + bni + rr * bnh);
            H0b[lg * 4 + i][c] = f2b((1.f - zz) * nn);
        }
    }
    __syncthreads();

    // ---- phase 3: gru1 (h0=0) -> HLf f32; also issue Ssum loads early ----
    float4 ssA[4], ssB[4];
    {
        const float* p1 = Ssum + (size_t)(r0 + lm) * 128 + lg * 8;
#pragma unroll
        for (int ks = 0; ks < 4; ++ks) {
            ssA[ks] = *reinterpret_cast<const float4*>(p1 + ks * 32);
            ssB[ks] = *reinterpret_cast<const float4*>(p1 + ks * 32 + 4);
        }
        bf16x8 af[4], bw[3][4];
#pragma unroll
        for (int ks = 0; ks < 4; ++ks) {
            af[ks] = ldfrag(&H0b[lm][ks * 32 + lg * 8]);
#pragma unroll
            for (int g = 0; g < 3; ++g)
                bw[g][ks] = ldfrag(WIH1 + (g * 128 + c) * 128 + ks * 32 + lg * 8);
        }
        floatx4 aR{0,0,0,0}, aZ{0,0,0,0}, aN{0,0,0,0};
#pragma unroll
        for (int ks = 0; ks < 4; ++ks) {
            aR = MFMA(af[ks], bw[0][ks], aR);
            aZ = MFMA(af[ks], bw[1][ks], aZ);
            aN = MFMA(af[ks], bw[2][ks], aN);
        }
        const float brr = bih1[c] + bhh1[c];
        const float bzz = bih1[128 + c] + bhh1[128 + c];
        const float bni = bih1[256 + c], bnh = bhh1[256 + c];
#pragma unroll
        for (int i = 0; i < 4; ++i) {
            const float rr = sigm(aR[i] + brr);
            const float zz = sigm(aZ[i] + bzz);
            const float nn = tanh_(aN[i] + bni + rr * bnh);
            HLf[lg * 4 + i][c] = (1.f - zz) * nn;
        }
    }
    __syncthreads();

    // ---- phase 4a: S = Ssum + HLf; elu(S @ gat_w) -> HBe ----
    {
        bf16x8 af[4], bw[4];
#pragma unroll
        for (int ks = 0; ks < 4; ++ks) {
            const float* hl = &HLf[lm][ks * 32 + lg * 8];
            float4 v  = *reinterpret_cast<const float4*>(hl);
            float4 v2 = *reinterpret_cast<const float4*>(hl + 4);
            short8 pk;
            pk[0] = (short)f2b(ssA[ks].x + v.x);  pk[1] = (short)f2b(ssA[ks].y + v.y);
            pk[2] = (short)f2b(ssA[ks].z + v.z);  pk[3] = (short)f2b(ssA[ks].w + v.w);
            pk[4] = (short)f2b(ssB[ks].x + v2.x); pk[5] = (short)f2b(ssB[ks].y + v2.y);
            pk[6] = (short)f2b(ssB[ks].z + v2.z); pk[7] = (short)f2b(ssB[ks].w + v2.w);
            af[ks] = __builtin_bit_cast(bf16x8, pk);
            bw[ks] = ldfrag(GATWT + c * 128 + ks * 32 + lg * 8);
        }
        floatx4 acc = {0.f, 0.f, 0.f, 0.f};
#pragma unroll
        for (int ks = 0; ks < 4; ++ks) acc = MFMA(af[ks], bw[ks], acc);
#pragma unroll
        for (int i = 0; i < 4; ++i) {
            float x = acc[i];
            x = x > 0.f ? x : (__expf(x) - 1.f);            // elu
            HBe[lg * 4 + i][c] = f2b(x);
        }
    }
    __syncthreads();

    // ---- phase 4b: relu(. @ ev1 + b1) -> XBf ----
    {
        bf16x8 af[4], bw[4];
#pragma unroll
        for (int ks = 0; ks < 4; ++ks) {
            af[ks] = ldfrag(&HBe[lm][ks * 32 + lg * 8]);
            bw[ks] = ldfrag(EV1T + c * 128 + ks * 32 + lg * 8);
        }
        floatx4 acc = {0.f, 0.f, 0.f, 0.f};
#pragma unroll
        for (int ks = 0; ks < 4; ++ks) acc = MFMA(af[ks], bw[ks], acc);
        const float bias = ev1b[c];
#pragma unroll
        for (int i = 0; i < 4; ++i) {
            float v = acc[i] + bias;
            XBf[lg * 4 + i][c] = v > 0.f ? v : 0.f;         // relu
        }
    }
    __syncthreads();

    // ---- phase 4c: out = XBf @ ev2 + b2 ----
    {
        const int row = threadIdx.x >> 5, l5 = threadIdx.x & 31;
        float sacc = 0.f;
#pragma unroll
        for (int j = 0; j < 4; ++j) {
            const int cc = l5 * 4 + j;
            sacc += XBf[row][cc] * ev2w[cc];
        }
#pragma unroll
        for (int d = 1; d < 32; d <<= 1) sacc += __shfl_xor(sacc, d, 64);
        if (l5 == 0) out[r0 + row] = sacc + ev2b[0];
    }
}

// ---------------------------------------------------------------------------
extern "C" void kernel_launch(void* const* d_in, const int* in_sizes, int n_in,
                              void* d_out, int out_size, void* d_ws, size_t ws_size,
                              hipStream_t stream)
{
    (void)in_sizes; (void)n_in; (void)out_size; (void)ws_size;
    const float* s       = (const float*)d_in[0];
    const float* a       = (const float*)d_in[1];
    const float* ue_l1_w = (const float*)d_in[2];
    const float* ue_l1_b = (const float*)d_in[3];
    const float* ue_l2_w = (const float*)d_in[4];
    const float* ue_l2_b = (const float*)d_in[5];
    const float* ue_wih0 = (const float*)d_in[6];
    const float* ue_whh0 = (const float*)d_in[7];
    const float* ue_bih0 = (const float*)d_in[8];
    const float* ue_bhh0 = (const float*)d_in[9];
    const float* ue_wih1 = (const float*)d_in[10];
    const float* ue_whh1 = (const float*)d_in[11];
    const float* ue_bih1 = (const float*)d_in[12];
    const float* ue_bhh1 = (const float*)d_in[13];
    const float* bs_l1_w = (const float*)d_in[14];
    const float* bs_l1_b = (const float*)d_in[15];
    const float* bs_l2_w = (const float*)d_in[16];
    const float* bs_l2_b = (const float*)d_in[17];
    const float* bs_wih0 = (const float*)d_in[18];
    const float* bs_bih0 = (const float*)d_in[20];
    const float* bs_bhh0 = (const float*)d_in[21];
    const float* bs_wih1 = (const float*)d_in[22];
    const float* bs_bih1 = (const float*)d_in[24];
    const float* bs_bhh1 = (const float*)d_in[25];
    const float* gat_w   = (const float*)d_in[26];
    const float* ev1_w   = (const float*)d_in[29];
    const float* ev1_b   = (const float*)d_in[30];
    const float* ev2_w   = (const float*)d_in[31];
    const float* ev2_b   = (const float*)d_in[32];

    char* ws = (char*)d_ws;
    u16*   wb   = (u16*)ws;
    u16*   X2   = (u16*)(ws + WB_X2);
    u16*   Y0   = (u16*)(ws + WB_Y0);
    float* SSUM = (float*)(ws + WB_SSUM);

    k_prep<<<256, 256, 0, stream>>>(ue_l1_w, ue_l2_w, ue_wih0, ue_whh0,
                                    ue_wih1, ue_whh1, bs_l1_w, bs_l2_w,
                                    bs_wih0, bs_wih1, gat_w, ev1_w, wb);
    k_ue_l1l2<<<1024, 512, 0, stream>>>(s, a, wb + O_UE_W1T, ue_l1_b,
                                        wb + O_UE_W2T, ue_l2_b, X2);
    k_scan<0><<<256, 512, 0, stream>>>(X2, wb + O_UE_WIH0, wb + O_UE_WHH0,
                                       ue_bih0, ue_bhh0, Y0, nullptr);
    k_scan<1><<<256, 512, 0, stream>>>(Y0, wb + O_UE_WIH1, wb + O_UE_WHH1,
                                       ue_bih1, ue_bhh1, nullptr, SSUM);
    k_bs_final<<<256, 512, 0, stream>>>(s, a, wb + O_BS_W1T, bs_l1_b,
                                        wb + O_BS_W2T, bs_l2_b,
                                        wb + O_BS_WIH0, bs_bih0, bs_bhh0,
                                        wb + O_BS_WIH1, bs_bih1, bs_bhh1,
                                        SSUM, wb + O_GATWT, wb + O_EV1T,
                                        ev1_b, ev2_w, ev2_b, (float*)d_out);
}